// Round 1
// baseline (4862.573 us; speedup 1.0000x reference)
//
#include <hip/hip_runtime.h>

#define NUSER 100000
#define NITEM 50000
#define NEDGE 640000
#define NLINK 200000
// F0 = F1 = 128, F2 = 64

// ---------------------------------------------------------------------------
// Edge-degree counts (float so the divide is cheap later). One thread/edge.
// ---------------------------------------------------------------------------
__global__ void count_kernel(const int* __restrict__ src, const int* __restrict__ dst,
                             float* __restrict__ cnt_u, float* __restrict__ cnt_i) {
    int e = blockIdx.x * blockDim.x + threadIdx.x;
    if (e >= NEDGE) return;
    unsafeAtomicAdd(&cnt_u[src[e]], 1.0f);
    unsafeAtomicAdd(&cnt_i[dst[e]], 1.0f);
}

// ---------------------------------------------------------------------------
// Scatter-aggregate both directions at width 128.
// 32 threads per edge, float4 per thread (coalesced 512B row reads).
//   agg_i[dst] += xu[src];  agg_u[src] += xi[dst];
// ---------------------------------------------------------------------------
__global__ void scatter128_kernel(const float* __restrict__ xu, const float* __restrict__ xi,
                                  const int* __restrict__ src, const int* __restrict__ dst,
                                  float* __restrict__ agg_i, float* __restrict__ agg_u) {
    int t = blockIdx.x * blockDim.x + threadIdx.x;
    int e = t >> 5;
    int q = (t & 31) * 4;
    if (e >= NEDGE) return;
    int s = src[e], d = dst[e];
    const float4 vu = *(const float4*)(xu + (size_t)s * 128 + q);
    const float4 vi = *(const float4*)(xi + (size_t)d * 128 + q);
    float* pi = agg_i + (size_t)d * 128 + q;
    float* pu = agg_u + (size_t)s * 128 + q;
    unsafeAtomicAdd(pi + 0, vu.x); unsafeAtomicAdd(pi + 1, vu.y);
    unsafeAtomicAdd(pi + 2, vu.z); unsafeAtomicAdd(pi + 3, vu.w);
    unsafeAtomicAdd(pu + 0, vi.x); unsafeAtomicAdd(pu + 1, vi.y);
    unsafeAtomicAdd(pu + 2, vi.z); unsafeAtomicAdd(pu + 3, vi.w);
}

// ---------------------------------------------------------------------------
// Fused SAGE transform: out[row,f] = [relu]( (agg[row,:]/max(cnt,1)) @ Wl[:,f]
//                                            + bias[f] + xself[row,:] @ Wr[:,f] )
// ROWS rows per block so the 64KB weight matrices are re-read 1/ROWS as often.
// blockDim == FOUT; one output column per thread.
// ---------------------------------------------------------------------------
template <int FOUT, int ROWS, bool RELU>
__global__ __launch_bounds__(FOUT) void sage_kernel(
    const float* __restrict__ agg, const float* __restrict__ cnt,
    const float* __restrict__ xself,
    const float* __restrict__ Wl, const float* __restrict__ bias,
    const float* __restrict__ Wr,
    float* __restrict__ out, int n)
{
    __shared__ float a_s[ROWS][128];
    __shared__ float x_s[ROWS][128];
    const int f = threadIdx.x;
    const int row0 = blockIdx.x * ROWS;

    for (int r = 0; r < ROWS; ++r) {
        int row = row0 + r;
        if (row < n) {
            float inv = 1.0f / fmaxf(cnt[row], 1.0f);
            for (int k = f; k < 128; k += FOUT) {
                a_s[r][k] = agg[(size_t)row * 128 + k] * inv;
                x_s[r][k] = xself[(size_t)row * 128 + k];
            }
        }
    }
    __syncthreads();

    float acc[ROWS];
    const float bv = bias[f];
#pragma unroll
    for (int r = 0; r < ROWS; ++r) acc[r] = bv;

    for (int k4 = 0; k4 < 128; k4 += 4) {
        float wl0 = Wl[(k4 + 0) * FOUT + f];
        float wl1 = Wl[(k4 + 1) * FOUT + f];
        float wl2 = Wl[(k4 + 2) * FOUT + f];
        float wl3 = Wl[(k4 + 3) * FOUT + f];
        float wr0 = Wr[(k4 + 0) * FOUT + f];
        float wr1 = Wr[(k4 + 1) * FOUT + f];
        float wr2 = Wr[(k4 + 2) * FOUT + f];
        float wr3 = Wr[(k4 + 3) * FOUT + f];
#pragma unroll
        for (int r = 0; r < ROWS; ++r) {
            float4 av = *(const float4*)&a_s[r][k4];
            float4 xv = *(const float4*)&x_s[r][k4];
            acc[r] += av.x * wl0 + av.y * wl1 + av.z * wl2 + av.w * wl3
                    + xv.x * wr0 + xv.y * wr1 + xv.z * wr2 + xv.w * wr3;
        }
    }

    for (int r = 0; r < ROWS; ++r) {
        int row = row0 + r;
        if (row < n) {
            float v = acc[r];
            if (RELU) v = fmaxf(v, 0.0f);
            out[(size_t)row * FOUT + f] = v;
        }
    }
}

// ---------------------------------------------------------------------------
// Link head: pred[l] = dot64(h_u2[el_src[l]], h_i2[el_dst[l]]).
// One wave (64 lanes) per link, shuffle reduce.
// ---------------------------------------------------------------------------
__global__ void predict_kernel(const int* __restrict__ el_src, const int* __restrict__ el_dst,
                               const float* __restrict__ hu, const float* __restrict__ hi,
                               float* __restrict__ out) {
    int t = blockIdx.x * blockDim.x + threadIdx.x;
    int l = t >> 6;
    int lane = t & 63;
    if (l >= NLINK) return;
    int u = el_src[l];
    int it = el_dst[l];
    float v = hu[(size_t)u * 64 + lane] * hi[(size_t)it * 64 + lane];
#pragma unroll
    for (int o = 32; o >= 1; o >>= 1) v += __shfl_down(v, o, 64);
    if (lane == 0) out[l] = v;
}

extern "C" void kernel_launch(void* const* d_in, const int* in_sizes, int n_in,
                              void* d_out, int out_size, void* d_ws, size_t ws_size,
                              hipStream_t stream) {
    const float* x_user = (const float*)d_in[0];
    const float* x_item = (const float*)d_in[1];
    const int*   src_u  = (const int*)d_in[2];
    const int*   dst_i  = (const int*)d_in[3];
    const int*   el_src = (const int*)d_in[4];
    const int*   el_dst = (const int*)d_in[5];
    const float* Wl_ui1 = (const float*)d_in[6];
    const float* b_ui1  = (const float*)d_in[7];
    const float* Wr_ui1 = (const float*)d_in[8];
    const float* Wl_iu1 = (const float*)d_in[9];
    const float* b_iu1  = (const float*)d_in[10];
    const float* Wr_iu1 = (const float*)d_in[11];
    const float* Wl_ui2 = (const float*)d_in[12];
    const float* b_ui2  = (const float*)d_in[13];
    const float* Wr_ui2 = (const float*)d_in[14];
    const float* Wl_iu2 = (const float*)d_in[15];
    const float* b_iu2  = (const float*)d_in[16];
    const float* Wr_iu2 = (const float*)d_in[17];
    float* out = (float*)d_out;

    // workspace layout (floats): total ~48.2M floats = ~193MB
    float* ws    = (float*)d_ws;
    float* cnt_i = ws;                               // NITEM
    float* cnt_u = cnt_i + NITEM;                    // NUSER
    float* agg_i = cnt_u + NUSER;                    // NITEM*128
    float* agg_u = agg_i + (size_t)NITEM * 128;      // NUSER*128
    float* h_i1  = agg_u + (size_t)NUSER * 128;      // NITEM*128
    float* h_u1  = h_i1 + (size_t)NITEM * 128;       // NUSER*128
    float* h_i2  = h_u1 + (size_t)NUSER * 128;       // NITEM*64
    float* h_u2  = h_i2 + (size_t)NITEM * 64;        // NUSER*64

    // zero counts + both aggregation buffers (contiguous prefix of ws)
    size_t zero1 = ((size_t)NITEM + NUSER + (size_t)(NITEM + NUSER) * 128) * sizeof(float);
    hipMemsetAsync(d_ws, 0, zero1, stream);

    // degrees (shared by both layers: same edge set)
    count_kernel<<<(NEDGE + 255) / 256, 256, 0, stream>>>(src_u, dst_i, cnt_u, cnt_i);

    // ---- layer 1 ----
    scatter128_kernel<<<(NEDGE * 32 + 255) / 256, 256, 0, stream>>>(
        x_user, x_item, src_u, dst_i, agg_i, agg_u);
    sage_kernel<128, 16, true><<<(NITEM + 15) / 16, 128, 0, stream>>>(
        agg_i, cnt_i, x_item, Wl_ui1, b_ui1, Wr_ui1, h_i1, NITEM);
    sage_kernel<128, 16, true><<<(NUSER + 15) / 16, 128, 0, stream>>>(
        agg_u, cnt_u, x_user, Wl_iu1, b_iu1, Wr_iu1, h_u1, NUSER);

    // ---- layer 2 ----
    hipMemsetAsync(agg_i, 0, (size_t)(NITEM + NUSER) * 128 * sizeof(float), stream);
    scatter128_kernel<<<(NEDGE * 32 + 255) / 256, 256, 0, stream>>>(
        h_u1, h_i1, src_u, dst_i, agg_i, agg_u);
    sage_kernel<64, 16, false><<<(NITEM + 15) / 16, 64, 0, stream>>>(
        agg_i, cnt_i, h_i1, Wl_ui2, b_ui2, Wr_ui2, h_i2, NITEM);
    sage_kernel<64, 16, false><<<(NUSER + 15) / 16, 64, 0, stream>>>(
        agg_u, cnt_u, h_u1, Wl_iu2, b_iu2, Wr_iu2, h_u2, NUSER);

    // ---- link prediction head ----
    predict_kernel<<<(NLINK * 64 + 255) / 256, 256, 0, stream>>>(
        el_src, el_dst, h_u2, h_i2, out);
}

// Round 2
// 887.990 us; speedup vs baseline: 5.4759x; 5.4759x over previous
//
#include <hip/hip_runtime.h>

#define NUSER 100000
#define NITEM 50000
#define NEDGE 640000
#define NLINK 200000
// F0 = F1 = 128, F2 = 64

// ---------------------------------------------------------------------------
// CSR build step 1: integer degree counts per node (both directions).
// ---------------------------------------------------------------------------
__global__ void count_kernel(const int* __restrict__ src, const int* __restrict__ dst,
                             int* __restrict__ cnt_u, int* __restrict__ cnt_i) {
    int e = blockIdx.x * blockDim.x + threadIdx.x;
    if (e >= NEDGE) return;
    atomicAdd(&cnt_u[src[e]], 1);
    atomicAdd(&cnt_i[dst[e]], 1);
}

// ---------------------------------------------------------------------------
// CSR build step 2: bucket offsets. Order of buckets is arbitrary (atomic
// counter), which is fine: gather only needs [end-cnt, end) to be this node's
// contiguous slice.
// ---------------------------------------------------------------------------
__global__ void offsets_kernel(const int* __restrict__ cnt, int* __restrict__ head,
                               int* __restrict__ counter, int n) {
    int i = blockIdx.x * blockDim.x + threadIdx.x;
    if (i >= n) return;
    head[i] = atomicAdd(counter, cnt[i]);
}

// ---------------------------------------------------------------------------
// CSR build step 3: fill neighbor lists (store the neighbor node id directly).
// After this kernel, head[x] == end offset of node x's slice.
// ---------------------------------------------------------------------------
__global__ void fill_kernel(const int* __restrict__ src, const int* __restrict__ dst,
                            int* __restrict__ head_u, int* __restrict__ head_i,
                            int* __restrict__ nbr_u, int* __restrict__ nbr_i) {
    int e = blockIdx.x * blockDim.x + threadIdx.x;
    if (e >= NEDGE) return;
    int s = src[e], d = dst[e];
    nbr_i[atomicAdd(&head_i[d], 1)] = s;
    nbr_u[atomicAdd(&head_u[s], 1)] = d;
}

// ---------------------------------------------------------------------------
// Gather mean-aggregation, width 128. One 64-lane wave per destination node;
// each lane owns 2 consecutive floats (wave reads 512B/row, coalesced).
// Writes the MEAN (divide folded in). Nodes with no edges write 0.
// ---------------------------------------------------------------------------
__global__ void gather_mean_kernel(const float* __restrict__ x,
                                   const int* __restrict__ nbr,
                                   const int* __restrict__ head,
                                   const int* __restrict__ cnt,
                                   float* __restrict__ agg, int n) {
    int t = blockIdx.x * blockDim.x + threadIdx.x;
    int w = t >> 6;
    int lane = t & 63;
    if (w >= n) return;
    int c = cnt[w];
    int end = head[w];
    int j = end - c;
    float ax = 0.0f, ay = 0.0f;
    for (; j + 1 < end; j += 2) {
        int s0 = nbr[j], s1 = nbr[j + 1];
        float2 v0 = *(const float2*)(x + (size_t)s0 * 128 + lane * 2);
        float2 v1 = *(const float2*)(x + (size_t)s1 * 128 + lane * 2);
        ax += v0.x + v1.x;
        ay += v0.y + v1.y;
    }
    if (j < end) {
        int s0 = nbr[j];
        float2 v0 = *(const float2*)(x + (size_t)s0 * 128 + lane * 2);
        ax += v0.x;
        ay += v0.y;
    }
    float inv = 1.0f / fmaxf((float)c, 1.0f);
    *(float2*)(agg + (size_t)w * 128 + lane * 2) = make_float2(ax * inv, ay * inv);
}

// ---------------------------------------------------------------------------
// Fused SAGE transform: out[row,f] = [relu]( agg[row,:] @ Wl[:,f] + bias[f]
//                                            + xself[row,:] @ Wr[:,f] )
// (agg is already the mean.) ROWS rows per block amortize weight re-reads.
// out may ALIAS agg (rows are staged to LDS before any write, and each block
// writes only rows it staged) -> no __restrict__ on agg/out.
// OSTRIDE lets layer-2 (FOUT=64) write in-place into a stride-128 buffer.
// ---------------------------------------------------------------------------
template <int FOUT, int ROWS, bool RELU, int OSTRIDE>
__global__ __launch_bounds__(FOUT) void sage_kernel(
    const float* agg, const float* __restrict__ xself,
    const float* __restrict__ Wl, const float* __restrict__ bias,
    const float* __restrict__ Wr,
    float* out, int n)
{
    __shared__ float a_s[ROWS][128];
    __shared__ float x_s[ROWS][128];
    const int f = threadIdx.x;
    const int row0 = blockIdx.x * ROWS;

    for (int r = 0; r < ROWS; ++r) {
        int row = row0 + r;
        if (row < n) {
            for (int k = f; k < 128; k += FOUT) {
                a_s[r][k] = agg[(size_t)row * 128 + k];
                x_s[r][k] = xself[(size_t)row * 128 + k];
            }
        }
    }
    __syncthreads();

    float acc[ROWS];
    const float bv = bias[f];
#pragma unroll
    for (int r = 0; r < ROWS; ++r) acc[r] = bv;

    for (int k4 = 0; k4 < 128; k4 += 4) {
        float wl0 = Wl[(k4 + 0) * FOUT + f];
        float wl1 = Wl[(k4 + 1) * FOUT + f];
        float wl2 = Wl[(k4 + 2) * FOUT + f];
        float wl3 = Wl[(k4 + 3) * FOUT + f];
        float wr0 = Wr[(k4 + 0) * FOUT + f];
        float wr1 = Wr[(k4 + 1) * FOUT + f];
        float wr2 = Wr[(k4 + 2) * FOUT + f];
        float wr3 = Wr[(k4 + 3) * FOUT + f];
#pragma unroll
        for (int r = 0; r < ROWS; ++r) {
            float4 av = *(const float4*)&a_s[r][k4];
            float4 xv = *(const float4*)&x_s[r][k4];
            acc[r] += av.x * wl0 + av.y * wl1 + av.z * wl2 + av.w * wl3
                    + xv.x * wr0 + xv.y * wr1 + xv.z * wr2 + xv.w * wr3;
        }
    }

    for (int r = 0; r < ROWS; ++r) {
        int row = row0 + r;
        if (row < n) {
            float v = acc[r];
            if (RELU) v = fmaxf(v, 0.0f);
            out[(size_t)row * OSTRIDE + f] = v;
        }
    }
}

// ---------------------------------------------------------------------------
// Link head: pred[l] = dot64(h_u2[el_src[l]], h_i2[el_dst[l]]).
// h buffers have row stride 128 (cols 0..63 valid). One wave per link.
// ---------------------------------------------------------------------------
__global__ void predict_kernel(const int* __restrict__ el_src, const int* __restrict__ el_dst,
                               const float* __restrict__ hu, const float* __restrict__ hi,
                               float* __restrict__ out) {
    int t = blockIdx.x * blockDim.x + threadIdx.x;
    int l = t >> 6;
    int lane = t & 63;
    if (l >= NLINK) return;
    int u = el_src[l];
    int it = el_dst[l];
    float v = hu[(size_t)u * 128 + lane] * hi[(size_t)it * 128 + lane];
#pragma unroll
    for (int o = 32; o >= 1; o >>= 1) v += __shfl_down(v, o, 64);
    if (lane == 0) out[l] = v;
}

extern "C" void kernel_launch(void* const* d_in, const int* in_sizes, int n_in,
                              void* d_out, int out_size, void* d_ws, size_t ws_size,
                              hipStream_t stream) {
    const float* x_user = (const float*)d_in[0];
    const float* x_item = (const float*)d_in[1];
    const int*   src_u  = (const int*)d_in[2];
    const int*   dst_i  = (const int*)d_in[3];
    const int*   el_src = (const int*)d_in[4];
    const int*   el_dst = (const int*)d_in[5];
    const float* Wl_ui1 = (const float*)d_in[6];
    const float* b_ui1  = (const float*)d_in[7];
    const float* Wr_ui1 = (const float*)d_in[8];
    const float* Wl_iu1 = (const float*)d_in[9];
    const float* b_iu1  = (const float*)d_in[10];
    const float* Wr_iu1 = (const float*)d_in[11];
    const float* Wl_ui2 = (const float*)d_in[12];
    const float* b_ui2  = (const float*)d_in[13];
    const float* Wr_ui2 = (const float*)d_in[14];
    const float* Wl_iu2 = (const float*)d_in[15];
    const float* b_iu2  = (const float*)d_in[16];
    const float* Wr_iu2 = (const float*)d_in[17];
    float* out = (float*)d_out;

    // ---- workspace layout ----
    // ints first: cnt_i, cnt_u, counters[2]  (memset region), head_i, head_u,
    //             nbr_i[E], nbr_u[E]
    // floats:     aggA_i[NITEM*128] (-> h_i1 in place)
    //             aggA_u[NUSER*128] (-> h_u1 in place)
    //             aggB_i[NITEM*128] (-> h_i2 in place, cols 0..63)
    //             aggB_u[NUSER*128] (-> h_u2 in place, cols 0..63)
    // total ~160 MB
    int* iw       = (int*)d_ws;
    int* cnt_i    = iw;                   // NITEM
    int* cnt_u    = cnt_i + NITEM;        // NUSER
    int* counters = cnt_u + NUSER;        // 2
    int* head_i   = counters + 2;         // NITEM
    int* head_u   = head_i + NITEM;       // NUSER
    int* nbr_i    = head_u + NUSER;       // NEDGE
    int* nbr_u    = nbr_i + NEDGE;        // NEDGE
    size_t int_total = (size_t)2 * NITEM + 2 * NUSER + 2 + 2 * NEDGE;
    size_t falign = (int_total + 3) & ~(size_t)3;   // 16B-align the float region
    float* aggA_i = (float*)d_ws + falign;
    float* aggA_u = aggA_i + (size_t)NITEM * 128;
    float* aggB_i = aggA_u + (size_t)NUSER * 128;
    float* aggB_u = aggB_i + (size_t)NITEM * 128;

    // zero counts + counters only (gather/fill fully overwrite everything else)
    hipMemsetAsync(d_ws, 0, ((size_t)NITEM + NUSER + 2) * sizeof(int), stream);

    // ---- CSR build (shared by both layers) ----
    count_kernel<<<(NEDGE + 255) / 256, 256, 0, stream>>>(src_u, dst_i, cnt_u, cnt_i);
    offsets_kernel<<<(NITEM + 255) / 256, 256, 0, stream>>>(cnt_i, head_i, counters + 0, NITEM);
    offsets_kernel<<<(NUSER + 255) / 256, 256, 0, stream>>>(cnt_u, head_u, counters + 1, NUSER);
    fill_kernel<<<(NEDGE + 255) / 256, 256, 0, stream>>>(src_u, dst_i, head_u, head_i, nbr_u, nbr_i);

    // ---- layer 1 ----
    gather_mean_kernel<<<((size_t)NITEM * 64 + 255) / 256, 256, 0, stream>>>(
        x_user, nbr_i, head_i, cnt_i, aggA_i, NITEM);
    gather_mean_kernel<<<((size_t)NUSER * 64 + 255) / 256, 256, 0, stream>>>(
        x_item, nbr_u, head_u, cnt_u, aggA_u, NUSER);
    sage_kernel<128, 16, true, 128><<<(NITEM + 15) / 16, 128, 0, stream>>>(
        aggA_i, x_item, Wl_ui1, b_ui1, Wr_ui1, aggA_i, NITEM);   // h_i1 in place
    sage_kernel<128, 16, true, 128><<<(NUSER + 15) / 16, 128, 0, stream>>>(
        aggA_u, x_user, Wl_iu1, b_iu1, Wr_iu1, aggA_u, NUSER);   // h_u1 in place

    // ---- layer 2 ----
    gather_mean_kernel<<<((size_t)NITEM * 64 + 255) / 256, 256, 0, stream>>>(
        aggA_u, nbr_i, head_i, cnt_i, aggB_i, NITEM);            // gather h_u1
    gather_mean_kernel<<<((size_t)NUSER * 64 + 255) / 256, 256, 0, stream>>>(
        aggA_i, nbr_u, head_u, cnt_u, aggB_u, NUSER);            // gather h_i1
    sage_kernel<64, 16, false, 128><<<(NITEM + 15) / 16, 64, 0, stream>>>(
        aggB_i, aggA_i, Wl_ui2, b_ui2, Wr_ui2, aggB_i, NITEM);   // h_i2 in place
    sage_kernel<64, 16, false, 128><<<(NUSER + 15) / 16, 64, 0, stream>>>(
        aggB_u, aggA_u, Wl_iu2, b_iu2, Wr_iu2, aggB_u, NUSER);   // h_u2 in place

    // ---- link prediction head ----
    predict_kernel<<<((size_t)NLINK * 64 + 255) / 256, 256, 0, stream>>>(
        el_src, el_dst, aggB_u, aggB_i, out);
}

// Round 4
// 475.386 us; speedup vs baseline: 10.2287x; 1.8679x over previous
//
#include <hip/hip_runtime.h>

#define NUSER 100000
#define NITEM 50000
#define NEDGE 640000
#define NLINK 200000
// F0 = F1 = 128, F2 = 64

typedef unsigned int  uint;
typedef unsigned short ushort_t;
typedef __attribute__((ext_vector_type(8))) short bf16x8;
typedef __attribute__((ext_vector_type(4))) float f32x4;
typedef __attribute__((ext_vector_type(4))) uint  u32x4;

__device__ __forceinline__ ushort_t f2bf(float f) {           // RNE f32 -> bf16
    uint u = __float_as_uint(f);
    u += 0x7FFFu + ((u >> 16) & 1u);
    return (ushort_t)(u >> 16);
}
__device__ __forceinline__ float bf2f(ushort_t h) { return __uint_as_float(((uint)h) << 16); }
__device__ __forceinline__ float lo16f(uint u) { return __uint_as_float(u << 16); }
__device__ __forceinline__ float hi16f(uint u) { return __uint_as_float(u & 0xFFFF0000u); }

// ---------------------------------------------------------------------------
// CSR build (same edge set reused by both layers)
// ---------------------------------------------------------------------------
__global__ void count_kernel(const int* __restrict__ src, const int* __restrict__ dst,
                             int* __restrict__ cnt_u, int* __restrict__ cnt_i) {
    int e = blockIdx.x * blockDim.x + threadIdx.x;
    if (e >= NEDGE) return;
    atomicAdd(&cnt_u[src[e]], 1);
    atomicAdd(&cnt_i[dst[e]], 1);
}

__global__ void offsets_kernel(const int* __restrict__ cnt, int* __restrict__ head,
                               int* __restrict__ counter, int n) {
    int i = blockIdx.x * blockDim.x + threadIdx.x;
    if (i >= n) return;
    head[i] = atomicAdd(counter, cnt[i]);
}

__global__ void fill_kernel(const int* __restrict__ src, const int* __restrict__ dst,
                            int* __restrict__ head_u, int* __restrict__ head_i,
                            int* __restrict__ nbr_u, int* __restrict__ nbr_i) {
    int e = blockIdx.x * blockDim.x + threadIdx.x;
    if (e >= NEDGE) return;
    int s = src[e], d = dst[e];
    nbr_i[atomicAdd(&head_i[d], 1)] = s;
    nbr_u[atomicAdd(&head_u[s], 1)] = d;
}

// ---------------------------------------------------------------------------
// Pack B = [Wl | Wr] (each 128 x FO, f32) into MFMA fragment order, split into
// bf16 hi/lo. Layout: Bh/Bl[nt][ks][lane][j] ; col = nt*16+(lane&15),
// k = ks*32+(lane>>4)*8+j. Thread t == (nt*4+ks)*64+lane writes 8 bf16 each.
// ---------------------------------------------------------------------------
__global__ void wprep_kernel(const float* __restrict__ Wl, const float* __restrict__ Wr,
                             int FO, int NT, ushort_t* __restrict__ Bh, ushort_t* __restrict__ Bl) {
    int t = blockIdx.x * blockDim.x + threadIdx.x;
    if (t >= NT * 256) return;
    int lane = t & 63, ks = (t >> 6) & 3, nt = t >> 8;
    int col = nt * 16 + (lane & 15);
    int k0 = ks * 32 + (lane >> 4) * 8;
    const float* W = (col < FO) ? Wl : Wr;
    int cc = (col < FO) ? col : col - FO;
#pragma unroll
    for (int j = 0; j < 8; ++j) {
        float v = W[(size_t)(k0 + j) * FO + cc];
        ushort_t h = f2bf(v);
        Bh[(size_t)t * 8 + j] = h;
        Bl[(size_t)t * 8 + j] = f2bf(v - bf2f(h));
    }
}

// ---------------------------------------------------------------------------
// GEMM: out[n x NO] = A[n x 128] @ B[128 x NO], NO = 2*FO, cols [0,FO) -> ymsg
// (bf16), cols [FO,NO) -> zout (bf16). ASPLIT: A is f32, split to hi/lo bf16
// during LDS staging (3 MFMA products). else: A is bf16 (2 products, B split).
// Block: 256 thr / 4 waves; 32 rows/block; wave owns NO/4 cols.
// LDS tiles XOR-swizzled per 16B chunk (chunk ^ (row&7)) -> 2-way reads (free).
// ---------------------------------------------------------------------------
template <int NO, bool ASPLIT>
__global__ __launch_bounds__(256) void gemm_kernel(const void* __restrict__ A_,
    const ushort_t* __restrict__ Bh, const ushort_t* __restrict__ Bl,
    ushort_t* __restrict__ ymsg, ushort_t* __restrict__ zout, int n)
{
    constexpr int CT = NO / 64;   // 16-col tiles per wave
    constexpr int FO = NO / 2;
    __shared__ u32x4 ashH[32][16];
    __shared__ u32x4 ashL[ASPLIT ? 32 : 1][16];
    const int tid = threadIdx.x;
    const int row0 = blockIdx.x * 32;

    if (ASPLIT) {
        const float* A = (const float*)A_;
#pragma unroll
        for (int i = 0; i < 2; ++i) {
            int idx = i * 256 + tid;
            int row = idx >> 4, ch = idx & 15;
            int grow = row0 + row;
            f32x4 f0 = {0.f, 0.f, 0.f, 0.f}, f1 = {0.f, 0.f, 0.f, 0.f};
            if (grow < n) {
                const f32x4* p = (const f32x4*)(A + (size_t)grow * 128 + ch * 8);
                f0 = p[0]; f1 = p[1];
            }
            float e[8];
#pragma unroll
            for (int j = 0; j < 4; ++j) { e[j] = f0[j]; e[4 + j] = f1[j]; }
            uint hv[4], lv[4];
#pragma unroll
            for (int j = 0; j < 4; ++j) {
                ushort_t h0 = f2bf(e[2 * j]), h1 = f2bf(e[2 * j + 1]);
                hv[j] = (uint)h0 | ((uint)h1 << 16);
                ushort_t l0 = f2bf(e[2 * j] - bf2f(h0)), l1 = f2bf(e[2 * j + 1] - bf2f(h1));
                lv[j] = (uint)l0 | ((uint)l1 << 16);
            }
            int sc = ch ^ (row & 7);
            u32x4 hq = {hv[0], hv[1], hv[2], hv[3]};
            u32x4 lq = {lv[0], lv[1], lv[2], lv[3]};
            ashH[row][sc] = hq;
            ashL[row][sc] = lq;
        }
    } else {
        const ushort_t* A = (const ushort_t*)A_;
#pragma unroll
        for (int i = 0; i < 2; ++i) {
            int idx = i * 256 + tid;
            int row = idx >> 4, ch = idx & 15;
            int grow = row0 + row;
            u32x4 q = {0u, 0u, 0u, 0u};
            if (grow < n) q = *(const u32x4*)(A + (size_t)grow * 128 + ch * 8);
            ashH[row][ch ^ (row & 7)] = q;
        }
    }
    __syncthreads();

    const int lane = tid & 63, wv = tid >> 6;
    const int lr = lane & 15, lg = lane >> 4;
    const int colbase = wv * (NO / 4);
    f32x4 acc[2][CT];
#pragma unroll
    for (int rt = 0; rt < 2; ++rt)
#pragma unroll
        for (int ct = 0; ct < CT; ++ct) { f32x4 zz = {0.f, 0.f, 0.f, 0.f}; acc[rt][ct] = zz; }

#pragma unroll
    for (int ks = 0; ks < 4; ++ks) {
        bf16x8 ah[2], al[2];
#pragma unroll
        for (int rt = 0; rt < 2; ++rt) {
            int row = rt * 16 + lr;
            int pos = (ks * 4 + lg) ^ (row & 7);
            ah[rt] = __builtin_bit_cast(bf16x8, ashH[row][pos]);
            if (ASPLIT) al[rt] = __builtin_bit_cast(bf16x8, ashL[row][pos]);
        }
#pragma unroll
        for (int ct = 0; ct < CT; ++ct) {
            int nt = (colbase >> 4) + ct;
            size_t off = ((size_t)(nt * 4 + ks) * 64 + lane) * 8;
            bf16x8 bh = __builtin_bit_cast(bf16x8, *(const u32x4*)(Bh + off));
            bf16x8 bl = __builtin_bit_cast(bf16x8, *(const u32x4*)(Bl + off));
#pragma unroll
            for (int rt = 0; rt < 2; ++rt) {
                acc[rt][ct] = __builtin_amdgcn_mfma_f32_16x16x32_bf16(ah[rt], bh, acc[rt][ct], 0, 0, 0);
                acc[rt][ct] = __builtin_amdgcn_mfma_f32_16x16x32_bf16(ah[rt], bl, acc[rt][ct], 0, 0, 0);
                if (ASPLIT)
                    acc[rt][ct] = __builtin_amdgcn_mfma_f32_16x16x32_bf16(al[rt], bh, acc[rt][ct], 0, 0, 0);
            }
        }
    }

    // C/D layout (m89-verified): col = lane&15, row = (lane>>4)*4 + reg
#pragma unroll
    for (int rt = 0; rt < 2; ++rt)
#pragma unroll
        for (int ct = 0; ct < CT; ++ct) {
            int col = colbase + ct * 16 + lr;
            bool ism = col < FO;
            ushort_t* dst = ism ? ymsg : zout;
            int cc = ism ? col : col - FO;
#pragma unroll
            for (int r = 0; r < 4; ++r) {
                int row = row0 + rt * 16 + lg * 4 + r;
                if (row < n) dst[(size_t)row * FO + cc] = f2bf(acc[rt][ct][r]);
            }
        }
}

// ---------------------------------------------------------------------------
// Gather + epilogue, width 128 (layer 1): h = relu(mean(ymsg[nbr]) + z + b),
// emitted as bf16. One wave/node, lane owns 2 cols (uint = 2 bf16), 4-unroll.
// ---------------------------------------------------------------------------
__global__ __launch_bounds__(256) void gather1_kernel(const ushort_t* __restrict__ ymsg,
    const int* __restrict__ nbr, const int* __restrict__ head, const int* __restrict__ cnt,
    const ushort_t* __restrict__ z, const float* __restrict__ bias,
    ushort_t* __restrict__ hout, int n)
{
    int w = (blockIdx.x << 2) + (threadIdx.x >> 6);
    if (w >= n) return;
    int lane = threadIdx.x & 63;
    int c = cnt[w], end = head[w];
    int j = end - c;
    const uint* Y = (const uint*)ymsg;
    float ax = 0.f, ay = 0.f;
    for (; j + 3 < end; j += 4) {
        int s0 = nbr[j], s1 = nbr[j + 1], s2 = nbr[j + 2], s3 = nbr[j + 3];
        uint u0 = Y[(size_t)s0 * 64 + lane];
        uint u1 = Y[(size_t)s1 * 64 + lane];
        uint u2 = Y[(size_t)s2 * 64 + lane];
        uint u3 = Y[(size_t)s3 * 64 + lane];
        ax += lo16f(u0) + lo16f(u1) + lo16f(u2) + lo16f(u3);
        ay += hi16f(u0) + hi16f(u1) + hi16f(u2) + hi16f(u3);
    }
    for (; j < end; ++j) {
        uint u = Y[(size_t)nbr[j] * 64 + lane];
        ax += lo16f(u); ay += hi16f(u);
    }
    float m = 1.f / fmaxf((float)c, 1.f);
    uint zu = ((const uint*)z)[(size_t)w * 64 + lane];
    float vx = fmaxf(ax * m + lo16f(zu) + bias[lane * 2], 0.f);
    float vy = fmaxf(ay * m + hi16f(zu) + bias[lane * 2 + 1], 0.f);
    ((uint*)hout)[(size_t)w * 64 + lane] = (uint)f2bf(vx) | ((uint)f2bf(vy) << 16);
}

// ---------------------------------------------------------------------------
// Gather + epilogue, width 64 (layer 2, no relu), f32 output for predict.
// ---------------------------------------------------------------------------
__global__ __launch_bounds__(256) void gather2_kernel(const ushort_t* __restrict__ ymsg,
    const int* __restrict__ nbr, const int* __restrict__ head, const int* __restrict__ cnt,
    const ushort_t* __restrict__ z, const float* __restrict__ bias,
    float* __restrict__ hout, int n)
{
    int w = (blockIdx.x << 2) + (threadIdx.x >> 6);
    if (w >= n) return;
    int lane = threadIdx.x & 63;
    int c = cnt[w], end = head[w];
    int j = end - c;
    float a = 0.f;
    for (; j + 3 < end; j += 4) {
        int s0 = nbr[j], s1 = nbr[j + 1], s2 = nbr[j + 2], s3 = nbr[j + 3];
        a += bf2f(ymsg[(size_t)s0 * 64 + lane]) + bf2f(ymsg[(size_t)s1 * 64 + lane])
           + bf2f(ymsg[(size_t)s2 * 64 + lane]) + bf2f(ymsg[(size_t)s3 * 64 + lane]);
    }
    for (; j < end; ++j) a += bf2f(ymsg[(size_t)nbr[j] * 64 + lane]);
    float m = 1.f / fmaxf((float)c, 1.f);
    float v = a * m + bf2f(z[(size_t)w * 64 + lane]) + bias[lane];
    hout[(size_t)w * 64 + lane] = v;
}

// ---------------------------------------------------------------------------
// Link head: pred[l] = dot64(h_u2[el_src[l]], h_i2[el_dst[l]]). One wave/link.
// ---------------------------------------------------------------------------
__global__ __launch_bounds__(256) void predict_kernel(const int* __restrict__ el_src,
    const int* __restrict__ el_dst, const float* __restrict__ hu,
    const float* __restrict__ hi, float* __restrict__ out)
{
    int l = (blockIdx.x << 2) + (threadIdx.x >> 6);
    if (l >= NLINK) return;
    int lane = threadIdx.x & 63;
    int u = el_src[l];
    int it = el_dst[l];
    float v = hu[(size_t)u * 64 + lane] * hi[(size_t)it * 64 + lane];
#pragma unroll
    for (int o = 32; o >= 1; o >>= 1) v += __shfl_down(v, o, 64);
    if (lane == 0) out[l] = v;
}

extern "C" void kernel_launch(void* const* d_in, const int* in_sizes, int n_in,
                              void* d_out, int out_size, void* d_ws, size_t ws_size,
                              hipStream_t stream) {
    const float* x_user = (const float*)d_in[0];
    const float* x_item = (const float*)d_in[1];
    const int*   src_u  = (const int*)d_in[2];
    const int*   dst_i  = (const int*)d_in[3];
    const int*   el_src = (const int*)d_in[4];
    const int*   el_dst = (const int*)d_in[5];
    const float* Wl_ui1 = (const float*)d_in[6];
    const float* b_ui1  = (const float*)d_in[7];
    const float* Wr_ui1 = (const float*)d_in[8];
    const float* Wl_iu1 = (const float*)d_in[9];
    const float* b_iu1  = (const float*)d_in[10];
    const float* Wr_iu1 = (const float*)d_in[11];
    const float* Wl_ui2 = (const float*)d_in[12];
    const float* b_ui2  = (const float*)d_in[13];
    const float* Wr_ui2 = (const float*)d_in[14];
    const float* Wl_iu2 = (const float*)d_in[15];
    const float* b_iu2  = (const float*)d_in[16];
    const float* Wr_iu2 = (const float*)d_in[17];
    float* out = (float*)d_out;

    // ---- workspace layout (byte offsets; total ~122 MB) ----
    char* W8 = (char*)d_ws;
    int* cnt_i    = (int*)W8;                         // 50000
    int* cnt_u    = cnt_i + NITEM;                    // 100000
    int* counters = cnt_u + NUSER;                    // 2
    int* head_i   = counters + 2;                     // 50000
    int* head_u   = head_i + NITEM;                   // 100000
    int* nbr_i    = head_u + NUSER;                   // 640000
    int* nbr_u    = nbr_i + NEDGE;                    // 640000  -> ends at int 1,580,002
    size_t off = 6320128;                             // ints padded/aligned

    ushort_t* Bh1u = (ushort_t*)(W8 + off); off += 65536;
    ushort_t* Bl1u = (ushort_t*)(W8 + off); off += 65536;
    ushort_t* Bh1i = (ushort_t*)(W8 + off); off += 65536;
    ushort_t* Bl1i = (ushort_t*)(W8 + off); off += 65536;
    ushort_t* Bh2u = (ushort_t*)(W8 + off); off += 32768;
    ushort_t* Bl2u = (ushort_t*)(W8 + off); off += 32768;
    ushort_t* Bh2i = (ushort_t*)(W8 + off); off += 32768;
    ushort_t* Bl2i = (ushort_t*)(W8 + off); off += 32768;   // off = 6,713,344

    ushort_t* h1_u = (ushort_t*)(W8 + off); off += (size_t)NUSER * 128 * 2;  // 25.6 MB
    ushort_t* h1_i = (ushort_t*)(W8 + off); off += (size_t)NITEM * 128 * 2;  // 12.8 MB

    size_t YB = off;                                  // 45,113,344
    // layer-1 view of Y region
    ushort_t* ymsg_u = (ushort_t*)(W8 + YB);
    ushort_t* ymsg_i = (ushort_t*)(W8 + YB + 25600000);
    ushort_t* z_u    = (ushort_t*)(W8 + YB + 38400000);
    ushort_t* z_i    = (ushort_t*)(W8 + YB + 64000000);
    // layer-2 view of Y region (layer-1 buffers dead by then)
    ushort_t* ymsg2_u = (ushort_t*)(W8 + YB);
    ushort_t* ymsg2_i = (ushort_t*)(W8 + YB + 12800000);
    ushort_t* z2_u    = (ushort_t*)(W8 + YB + 19200000);
    ushort_t* z2_i    = (ushort_t*)(W8 + YB + 32000000);
    float*    h2_u    = (float*)(W8 + YB + 38400000);
    float*    h2_i    = (float*)(W8 + YB + 64000000);

    size_t total_ws = YB + 76800000;                  // 121,913,344 bytes

    // zero the ENTIRE used workspace: guarantees every call starts from an
    // identical state (graph replays included) -- closes the class of
    // "read location holding previous-call leftovers" divergence. ~19us.
    hipMemsetAsync(d_ws, 0, total_ws, stream);

    // ---- CSR build ----
    count_kernel<<<(NEDGE + 255) / 256, 256, 0, stream>>>(src_u, dst_i, cnt_u, cnt_i);
    offsets_kernel<<<(NITEM + 255) / 256, 256, 0, stream>>>(cnt_i, head_i, counters + 0, NITEM);
    offsets_kernel<<<(NUSER + 255) / 256, 256, 0, stream>>>(cnt_u, head_u, counters + 1, NUSER);
    fill_kernel<<<(NEDGE + 255) / 256, 256, 0, stream>>>(src_u, dst_i, head_u, head_i, nbr_u, nbr_i);

    // ---- weight packing (fragment order, bf16 hi/lo) ----
    wprep_kernel<<<16, 256, 0, stream>>>(Wl_ui1, Wr_iu1, 128, 16, Bh1u, Bl1u);
    wprep_kernel<<<16, 256, 0, stream>>>(Wl_iu1, Wr_ui1, 128, 16, Bh1i, Bl1i);
    wprep_kernel<<<8, 256, 0, stream>>>(Wl_ui2, Wr_iu2, 64, 8, Bh2u, Bl2u);
    wprep_kernel<<<8, 256, 0, stream>>>(Wl_iu2, Wr_ui2, 64, 8, Bh2i, Bl2i);

    // ---- layer 1: transform first (linearity of mean-agg), then gather ----
    gemm_kernel<256, true><<<(NUSER + 31) / 32, 256, 0, stream>>>(
        x_user, Bh1u, Bl1u, ymsg_u, z_u, NUSER);
    gemm_kernel<256, true><<<(NITEM + 31) / 32, 256, 0, stream>>>(
        x_item, Bh1i, Bl1i, ymsg_i, z_i, NITEM);
    gather1_kernel<<<(NITEM + 3) / 4, 256, 0, stream>>>(
        ymsg_u, nbr_i, head_i, cnt_i, z_i, b_ui1, h1_i, NITEM);
    gather1_kernel<<<(NUSER + 3) / 4, 256, 0, stream>>>(
        ymsg_i, nbr_u, head_u, cnt_u, z_u, b_iu1, h1_u, NUSER);

    // ---- layer 2 ----
    gemm_kernel<128, false><<<(NUSER + 31) / 32, 256, 0, stream>>>(
        h1_u, Bh2u, Bl2u, ymsg2_u, z2_u, NUSER);
    gemm_kernel<128, false><<<(NITEM + 31) / 32, 256, 0, stream>>>(
        h1_i, Bh2i, Bl2i, ymsg2_i, z2_i, NITEM);
    gather2_kernel<<<(NITEM + 3) / 4, 256, 0, stream>>>(
        ymsg2_u, nbr_i, head_i, cnt_i, z2_i, b_ui2, h2_i, NITEM);
    gather2_kernel<<<(NUSER + 3) / 4, 256, 0, stream>>>(
        ymsg2_i, nbr_u, head_u, cnt_u, z2_u, b_iu2, h2_u, NUSER);

    // ---- link prediction head ----
    predict_kernel<<<(NLINK + 3) / 4, 256, 0, stream>>>(el_src, el_dst, h2_u, h2_i, out);
}

// Round 5
// 379.285 us; speedup vs baseline: 12.8204x; 1.2534x over previous
//
#include <hip/hip_runtime.h>

#define NUSER 100000
#define NITEM 50000
#define NEDGE 640000
#define NLINK 200000
#define GI 49   // ceil(NITEM/1024)
#define GU 98   // ceil(NUSER/1024)
// F0 = F1 = 128, F2 = 64

typedef unsigned int  uint;
typedef unsigned short ushort_t;
typedef __attribute__((ext_vector_type(8))) short bf16x8;
typedef __attribute__((ext_vector_type(4))) float f32x4;
typedef __attribute__((ext_vector_type(4))) uint  u32x4;

__device__ __forceinline__ ushort_t f2bf(float f) {           // RNE f32 -> bf16
    uint u = __float_as_uint(f);
    u += 0x7FFFu + ((u >> 16) & 1u);
    return (ushort_t)(u >> 16);
}
__device__ __forceinline__ float bf2f(ushort_t h) { return __uint_as_float(((uint)h) << 16); }
__device__ __forceinline__ float lo16f(uint u) { return __uint_as_float(u << 16); }
__device__ __forceinline__ float hi16f(uint u) { return __uint_as_float(u & 0xFFFF0000u); }

// ---------------------------------------------------------------------------
// CSR build step 1: integer degree counts per node (both directions).
// ---------------------------------------------------------------------------
__global__ void count_kernel(const int* __restrict__ src, const int* __restrict__ dst,
                             int* __restrict__ cnt_u, int* __restrict__ cnt_i) {
    int e = blockIdx.x * blockDim.x + threadIdx.x;
    if (e >= NEDGE) return;
    atomicAdd(&cnt_u[src[e]], 1);
    atomicAdd(&cnt_i[dst[e]], 1);
}

// ---------------------------------------------------------------------------
// Ordered exclusive scan of cnt -> head (so node-id ranges own contiguous nbr
// windows; required for the binned fill's locality). 3-kernel hierarchical.
// scan1: per-1024-chunk local exclusive scan + chunk sum.
// ---------------------------------------------------------------------------
__global__ __launch_bounds__(256) void scan1_kernel(
    const int* __restrict__ cnt_i, const int* __restrict__ cnt_u,
    int* __restrict__ head_i, int* __restrict__ head_u,
    int* __restrict__ bsum_i, int* __restrict__ bsum_u)
{
    __shared__ int sh[256];
    int b = blockIdx.x, t = threadIdx.x;
    const int* cnt; int* head; int* bsum; int n, cb;
    if (b < GI) { cnt = cnt_i; head = head_i; bsum = bsum_i; n = NITEM; cb = b; }
    else        { cnt = cnt_u; head = head_u; bsum = bsum_u; n = NUSER; cb = b - GI; }
    int base = cb * 1024 + t * 4;
    int4 v = {0, 0, 0, 0};
    if (base + 3 < n) v = *(const int4*)(cnt + base);
    else {
        if (base + 0 < n) v.x = cnt[base + 0];
        if (base + 1 < n) v.y = cnt[base + 1];
        if (base + 2 < n) v.z = cnt[base + 2];
    }
    int s = v.x + v.y + v.z + v.w;
    sh[t] = s;
    __syncthreads();
    for (int o = 1; o < 256; o <<= 1) {
        int a = (t >= o) ? sh[t - o] : 0;
        __syncthreads();
        sh[t] += a;
        __syncthreads();
    }
    int excl = sh[t] - s;
    if (t == 255) bsum[cb] = sh[255];
    if (base + 0 < n) head[base + 0] = excl;
    if (base + 1 < n) head[base + 1] = excl + v.x;
    if (base + 2 < n) head[base + 2] = excl + v.x + v.y;
    if (base + 3 < n) head[base + 3] = excl + v.x + v.y + v.z;
}

// scan2: single block, exclusive-scan both chunk-sum arrays in LDS.
__global__ __launch_bounds__(256) void scan2_kernel(int* __restrict__ bsum_i,
                                                    int* __restrict__ bsum_u) {
    __shared__ int sh[256];
    int t = threadIdx.x;
    int orig = (t < GI) ? bsum_i[t] : 0;
    sh[t] = orig; __syncthreads();
    for (int o = 1; o < 256; o <<= 1) {
        int a = (t >= o) ? sh[t - o] : 0; __syncthreads(); sh[t] += a; __syncthreads();
    }
    if (t < GI) bsum_i[t] = sh[t] - orig;
    __syncthreads();
    int orig2 = (t < GU) ? bsum_u[t] : 0;
    sh[t] = orig2; __syncthreads();
    for (int o = 1; o < 256; o <<= 1) {
        int a = (t >= o) ? sh[t - o] : 0; __syncthreads(); sh[t] += a; __syncthreads();
    }
    if (t < GU) bsum_u[t] = sh[t] - orig2;
}

// scan3: add chunk offsets back.
__global__ __launch_bounds__(256) void scan3_kernel(
    int* __restrict__ head_i, int* __restrict__ head_u,
    const int* __restrict__ bsum_i, const int* __restrict__ bsum_u)
{
    int b = blockIdx.x, t = threadIdx.x;
    int* head; const int* bsum; int n, cb;
    if (b < GI) { head = head_i; bsum = bsum_i; n = NITEM; cb = b; }
    else        { head = head_u; bsum = bsum_u; n = NUSER; cb = b - GI; }
    int add = bsum[cb];
    int base = cb * 1024 + t * 4;
#pragma unroll
    for (int k = 0; k < 4; ++k)
        if (base + k < n) head[base + k] += add;
}

// ---------------------------------------------------------------------------
// Binned fill: 8 node-range passes per direction, pass-major block order.
// With ORDERED head offsets each pass's nbr stores land in a contiguous
// ~320KB window (L2-resident) -> full-line writeback amplification gone.
// head[x] ends as the END offset of x's slice (gather uses end-cnt..end).
// ---------------------------------------------------------------------------
#define FCHUNK 2048
#define FNCH   313   // ceil(NEDGE / FCHUNK)
__global__ __launch_bounds__(256) void fillb_kernel(
    const int* __restrict__ src, const int* __restrict__ dst,
    int* __restrict__ head_i, int* __restrict__ head_u,
    int* __restrict__ nbr_i, int* __restrict__ nbr_u)
{
    int b = blockIdx.x;
    int pass = b / (2 * FNCH);
    int rem  = b % (2 * FNCH);
    int dir  = rem / FNCH;          // 0: item-dir (bucket by dst), 1: user-dir (by src)
    int base = (rem % FNCH) * FCHUNK;
    int e_end = min(base + FCHUNK, NEDGE);
    if (dir == 0) {
        int lo = pass * (NITEM / 8), hi = lo + NITEM / 8;
        for (int e = base + threadIdx.x; e < e_end; e += 256) {
            int d = dst[e];
            if (d >= lo && d < hi) nbr_i[atomicAdd(&head_i[d], 1)] = src[e];
        }
    } else {
        int lo = pass * (NUSER / 8), hi = lo + NUSER / 8;
        for (int e = base + threadIdx.x; e < e_end; e += 256) {
            int s = src[e];
            if (s >= lo && s < hi) nbr_u[atomicAdd(&head_u[s], 1)] = dst[e];
        }
    }
}

// ---------------------------------------------------------------------------
// Pack all 4 B = [Wl | Wr] weight pairs into MFMA fragment order, bf16 hi/lo.
// Layout: Bh/Bl[nt][ks][lane][j]; col = nt*16+(lane&15), k = ks*32+(lane>>4)*8+j.
// ---------------------------------------------------------------------------
__global__ __launch_bounds__(256) void wprep_kernel(
    const float* __restrict__ Wl0, const float* __restrict__ Wr0,
    const float* __restrict__ Wl1, const float* __restrict__ Wr1,
    const float* __restrict__ Wl2, const float* __restrict__ Wr2,
    const float* __restrict__ Wl3, const float* __restrict__ Wr3,
    ushort_t* __restrict__ Bh0, ushort_t* __restrict__ Bl0,
    ushort_t* __restrict__ Bh1, ushort_t* __restrict__ Bl1,
    ushort_t* __restrict__ Bh2, ushort_t* __restrict__ Bl2,
    ushort_t* __restrict__ Bh3, ushort_t* __restrict__ Bl3)
{
    int b = blockIdx.x;
    const float *Wl, *Wr; ushort_t *Bh, *Bl; int FO, t;
    if (b < 16)      { Wl = Wl0; Wr = Wr0; Bh = Bh0; Bl = Bl0; FO = 128; t = b * 256 + threadIdx.x; }
    else if (b < 32) { Wl = Wl1; Wr = Wr1; Bh = Bh1; Bl = Bl1; FO = 128; t = (b - 16) * 256 + threadIdx.x; }
    else if (b < 40) { Wl = Wl2; Wr = Wr2; Bh = Bh2; Bl = Bl2; FO = 64;  t = (b - 32) * 256 + threadIdx.x; }
    else             { Wl = Wl3; Wr = Wr3; Bh = Bh3; Bl = Bl3; FO = 64;  t = (b - 40) * 256 + threadIdx.x; }
    int lane = t & 63, ks = (t >> 6) & 3, nt = t >> 8;
    int col = nt * 16 + (lane & 15);
    int k0 = ks * 32 + (lane >> 4) * 8;
    const float* W = (col < FO) ? Wl : Wr;
    int cc = (col < FO) ? col : col - FO;
#pragma unroll
    for (int j = 0; j < 8; ++j) {
        float v = W[(size_t)(k0 + j) * FO + cc];
        ushort_t h = f2bf(v);
        Bh[(size_t)t * 8 + j] = h;
        Bl[(size_t)t * 8 + j] = f2bf(v - bf2f(h));
    }
}

// ---------------------------------------------------------------------------
// GEMM (both node types in one dispatch): out[n x NO] = A[n x 128] @ B[128 x NO],
// cols [0,FO) -> ymsg (bf16), [FO,NO) -> zout (bf16). ASPLIT: A f32, hi/lo
// split in staging (3 MFMA products); else A bf16 (2 products, B split).
// 256 thr / 4 waves; 32 rows/block; LDS 16B-chunk XOR swizzle (2-way = free).
// ---------------------------------------------------------------------------
template <int NO, bool ASPLIT>
__global__ __launch_bounds__(256) void gemm_kernel(
    const void* __restrict__ A0, const void* __restrict__ A1,
    const ushort_t* __restrict__ Bh0, const ushort_t* __restrict__ Bl0,
    const ushort_t* __restrict__ Bh1, const ushort_t* __restrict__ Bl1,
    ushort_t* __restrict__ y0, ushort_t* __restrict__ z0,
    ushort_t* __restrict__ y1, ushort_t* __restrict__ z1,
    int n0, int n1, int nb0)
{
    constexpr int CT = NO / 64;
    constexpr int FO = NO / 2;
    __shared__ u32x4 ashH[32][16];
    __shared__ u32x4 ashL[ASPLIT ? 32 : 1][16];
    const int tid = threadIdx.x;
    const void* A_; const ushort_t *Bh, *Bl; ushort_t *ymsg, *zout; int n, row0;
    if ((int)blockIdx.x < nb0) { A_ = A0; Bh = Bh0; Bl = Bl0; ymsg = y0; zout = z0; n = n0; row0 = blockIdx.x * 32; }
    else { A_ = A1; Bh = Bh1; Bl = Bl1; ymsg = y1; zout = z1; n = n1; row0 = (blockIdx.x - nb0) * 32; }

    if (ASPLIT) {
        const float* A = (const float*)A_;
#pragma unroll
        for (int i = 0; i < 2; ++i) {
            int idx = i * 256 + tid;
            int row = idx >> 4, ch = idx & 15;
            int grow = row0 + row;
            f32x4 f0 = {0.f, 0.f, 0.f, 0.f}, f1 = {0.f, 0.f, 0.f, 0.f};
            if (grow < n) {
                const f32x4* p = (const f32x4*)((const float*)A + (size_t)grow * 128 + ch * 8);
                f0 = p[0]; f1 = p[1];
            }
            float e[8];
#pragma unroll
            for (int j = 0; j < 4; ++j) { e[j] = f0[j]; e[4 + j] = f1[j]; }
            uint hv[4], lv[4];
#pragma unroll
            for (int j = 0; j < 4; ++j) {
                ushort_t h0 = f2bf(e[2 * j]), h1 = f2bf(e[2 * j + 1]);
                hv[j] = (uint)h0 | ((uint)h1 << 16);
                ushort_t l0 = f2bf(e[2 * j] - bf2f(h0)), l1 = f2bf(e[2 * j + 1] - bf2f(h1));
                lv[j] = (uint)l0 | ((uint)l1 << 16);
            }
            int sc = ch ^ (row & 7);
            u32x4 hq = {hv[0], hv[1], hv[2], hv[3]};
            u32x4 lq = {lv[0], lv[1], lv[2], lv[3]};
            ashH[row][sc] = hq;
            ashL[row][sc] = lq;
        }
    } else {
        const ushort_t* A = (const ushort_t*)A_;
#pragma unroll
        for (int i = 0; i < 2; ++i) {
            int idx = i * 256 + tid;
            int row = idx >> 4, ch = idx & 15;
            int grow = row0 + row;
            u32x4 q = {0u, 0u, 0u, 0u};
            if (grow < n) q = *(const u32x4*)(A + (size_t)grow * 128 + ch * 8);
            ashH[row][ch ^ (row & 7)] = q;
        }
    }
    __syncthreads();

    const int lane = tid & 63, wv = tid >> 6;
    const int lr = lane & 15, lg = lane >> 4;
    const int colbase = wv * (NO / 4);
    f32x4 acc[2][CT];
#pragma unroll
    for (int rt = 0; rt < 2; ++rt)
#pragma unroll
        for (int ct = 0; ct < CT; ++ct) { f32x4 zz = {0.f, 0.f, 0.f, 0.f}; acc[rt][ct] = zz; }

#pragma unroll
    for (int ks = 0; ks < 4; ++ks) {
        bf16x8 ah[2], al[2];
#pragma unroll
        for (int rt = 0; rt < 2; ++rt) {
            int row = rt * 16 + lr;
            int pos = (ks * 4 + lg) ^ (row & 7);
            ah[rt] = __builtin_bit_cast(bf16x8, ashH[row][pos]);
            if (ASPLIT) al[rt] = __builtin_bit_cast(bf16x8, ashL[row][pos]);
        }
#pragma unroll
        for (int ct = 0; ct < CT; ++ct) {
            int nt = (colbase >> 4) + ct;
            size_t off = ((size_t)(nt * 4 + ks) * 64 + lane) * 8;
            bf16x8 bh = __builtin_bit_cast(bf16x8, *(const u32x4*)(Bh + off));
            bf16x8 bl = __builtin_bit_cast(bf16x8, *(const u32x4*)(Bl + off));
#pragma unroll
            for (int rt = 0; rt < 2; ++rt) {
                acc[rt][ct] = __builtin_amdgcn_mfma_f32_16x16x32_bf16(ah[rt], bh, acc[rt][ct], 0, 0, 0);
                acc[rt][ct] = __builtin_amdgcn_mfma_f32_16x16x32_bf16(ah[rt], bl, acc[rt][ct], 0, 0, 0);
                if (ASPLIT)
                    acc[rt][ct] = __builtin_amdgcn_mfma_f32_16x16x32_bf16(al[rt], bh, acc[rt][ct], 0, 0, 0);
            }
        }
    }

    // C/D layout (m89-verified): col = lane&15, row = (lane>>4)*4 + reg
#pragma unroll
    for (int rt = 0; rt < 2; ++rt)
#pragma unroll
        for (int ct = 0; ct < CT; ++ct) {
            int col = colbase + ct * 16 + lr;
            bool ism = col < FO;
            ushort_t* dst = ism ? ymsg : zout;
            int cc = ism ? col : col - FO;
#pragma unroll
            for (int r = 0; r < 4; ++r) {
                int row = row0 + rt * 16 + lg * 4 + r;
                if (row < n) dst[(size_t)row * FO + cc] = f2bf(acc[rt][ct][r]);
            }
        }
}

// ---------------------------------------------------------------------------
// Layer-1 gather + epilogue (items THEN users in one dispatch), width 128:
// h1 = relu(mean(ymsg[nbr]) + z + b) as bf16. One wave/node, lane owns 2 cols.
// ---------------------------------------------------------------------------
__global__ __launch_bounds__(256) void gather1_kernel(
    const ushort_t* __restrict__ ymsg_u, const ushort_t* __restrict__ ymsg_i,
    const int* __restrict__ nbr_i, const int* __restrict__ head_i, const int* __restrict__ cnt_i,
    const int* __restrict__ nbr_u, const int* __restrict__ head_u, const int* __restrict__ cnt_u,
    const ushort_t* __restrict__ z_i, const ushort_t* __restrict__ z_u,
    const float* __restrict__ b_ui, const float* __restrict__ b_iu,
    ushort_t* __restrict__ h1_i, ushort_t* __restrict__ h1_u)
{
    int w = (blockIdx.x << 2) + (threadIdx.x >> 6);
    const ushort_t *ym, *z; const int *nbr, *head, *cnt; const float* bias;
    ushort_t* hout; int node;
    if (w < NITEM) { ym = ymsg_u; nbr = nbr_i; head = head_i; cnt = cnt_i; z = z_i; bias = b_ui; hout = h1_i; node = w; }
    else if (w < NITEM + NUSER) { ym = ymsg_i; nbr = nbr_u; head = head_u; cnt = cnt_u; z = z_u; bias = b_iu; hout = h1_u; node = w - NITEM; }
    else return;
    int lane = threadIdx.x & 63;
    int c = cnt[node], end = head[node];
    int j = end - c;
    const uint* Y = (const uint*)ym;
    float ax = 0.f, ay = 0.f;
    for (; j + 7 < end; j += 8) {
        uint u0 = Y[(size_t)nbr[j + 0] * 64 + lane];
        uint u1 = Y[(size_t)nbr[j + 1] * 64 + lane];
        uint u2 = Y[(size_t)nbr[j + 2] * 64 + lane];
        uint u3 = Y[(size_t)nbr[j + 3] * 64 + lane];
        uint u4 = Y[(size_t)nbr[j + 4] * 64 + lane];
        uint u5 = Y[(size_t)nbr[j + 5] * 64 + lane];
        uint u6 = Y[(size_t)nbr[j + 6] * 64 + lane];
        uint u7 = Y[(size_t)nbr[j + 7] * 64 + lane];
        ax += lo16f(u0) + lo16f(u1) + lo16f(u2) + lo16f(u3)
            + lo16f(u4) + lo16f(u5) + lo16f(u6) + lo16f(u7);
        ay += hi16f(u0) + hi16f(u1) + hi16f(u2) + hi16f(u3)
            + hi16f(u4) + hi16f(u5) + hi16f(u6) + hi16f(u7);
    }
    for (; j + 1 < end; j += 2) {
        uint u0 = Y[(size_t)nbr[j + 0] * 64 + lane];
        uint u1 = Y[(size_t)nbr[j + 1] * 64 + lane];
        ax += lo16f(u0) + lo16f(u1);
        ay += hi16f(u0) + hi16f(u1);
    }
    if (j < end) {
        uint u0 = Y[(size_t)nbr[j] * 64 + lane];
        ax += lo16f(u0); ay += hi16f(u0);
    }
    float m = 1.f / fmaxf((float)c, 1.f);
    uint zu = ((const uint*)z)[(size_t)node * 64 + lane];
    float vx = fmaxf(ax * m + lo16f(zu) + bias[lane * 2], 0.f);
    float vy = fmaxf(ay * m + hi16f(zu) + bias[lane * 2 + 1], 0.f);
    ((uint*)hout)[(size_t)node * 64 + lane] = (uint)f2bf(vx) | ((uint)f2bf(vy) << 16);
}

// ---------------------------------------------------------------------------
// Layer-2 gather + epilogue (items THEN users), width 64, no relu, bf16 out.
// ---------------------------------------------------------------------------
__global__ __launch_bounds__(256) void gather2_kernel(
    const ushort_t* __restrict__ ymsg_u, const ushort_t* __restrict__ ymsg_i,
    const int* __restrict__ nbr_i, const int* __restrict__ head_i, const int* __restrict__ cnt_i,
    const int* __restrict__ nbr_u, const int* __restrict__ head_u, const int* __restrict__ cnt_u,
    const ushort_t* __restrict__ z_i, const ushort_t* __restrict__ z_u,
    const float* __restrict__ b_ui, const float* __restrict__ b_iu,
    ushort_t* __restrict__ h2_i, ushort_t* __restrict__ h2_u)
{
    int w = (blockIdx.x << 2) + (threadIdx.x >> 6);
    const ushort_t *ym, *z; const int *nbr, *head, *cnt; const float* bias;
    ushort_t* hout; int node;
    if (w < NITEM) { ym = ymsg_u; nbr = nbr_i; head = head_i; cnt = cnt_i; z = z_i; bias = b_ui; hout = h2_i; node = w; }
    else if (w < NITEM + NUSER) { ym = ymsg_i; nbr = nbr_u; head = head_u; cnt = cnt_u; z = z_u; bias = b_iu; hout = h2_u; node = w - NITEM; }
    else return;
    int lane = threadIdx.x & 63;
    int c = cnt[node], end = head[node];
    int j = end - c;
    float a = 0.f;
    for (; j + 7 < end; j += 8) {
        a += bf2f(ym[(size_t)nbr[j + 0] * 64 + lane]) + bf2f(ym[(size_t)nbr[j + 1] * 64 + lane])
           + bf2f(ym[(size_t)nbr[j + 2] * 64 + lane]) + bf2f(ym[(size_t)nbr[j + 3] * 64 + lane])
           + bf2f(ym[(size_t)nbr[j + 4] * 64 + lane]) + bf2f(ym[(size_t)nbr[j + 5] * 64 + lane])
           + bf2f(ym[(size_t)nbr[j + 6] * 64 + lane]) + bf2f(ym[(size_t)nbr[j + 7] * 64 + lane]);
    }
    for (; j + 1 < end; j += 2)
        a += bf2f(ym[(size_t)nbr[j] * 64 + lane]) + bf2f(ym[(size_t)nbr[j + 1] * 64 + lane]);
    if (j < end) a += bf2f(ym[(size_t)nbr[j] * 64 + lane]);
    float m = 1.f / fmaxf((float)c, 1.f);
    float v = a * m + bf2f(z[(size_t)node * 64 + lane]) + bias[lane];
    hout[(size_t)node * 64 + lane] = f2bf(v);
}

// ---------------------------------------------------------------------------
// Link head: pred[l] = dot64(h_u2[el_src[l]], h_i2[el_dst[l]]), bf16 h rows.
// ---------------------------------------------------------------------------
__global__ __launch_bounds__(256) void predict_kernel(
    const int* __restrict__ el_src, const int* __restrict__ el_dst,
    const ushort_t* __restrict__ hu, const ushort_t* __restrict__ hi,
    float* __restrict__ out)
{
    int l = (blockIdx.x << 2) + (threadIdx.x >> 6);
    if (l >= NLINK) return;
    int lane = threadIdx.x & 63;
    int u = el_src[l];
    int it = el_dst[l];
    float v = bf2f(hu[(size_t)u * 64 + lane]) * bf2f(hi[(size_t)it * 64 + lane]);
#pragma unroll
    for (int o = 32; o >= 1; o >>= 1) v += __shfl_down(v, o, 64);
    if (lane == 0) out[l] = v;
}

extern "C" void kernel_launch(void* const* d_in, const int* in_sizes, int n_in,
                              void* d_out, int out_size, void* d_ws, size_t ws_size,
                              hipStream_t stream) {
    const float* x_user = (const float*)d_in[0];
    const float* x_item = (const float*)d_in[1];
    const int*   src_u  = (const int*)d_in[2];
    const int*   dst_i  = (const int*)d_in[3];
    const int*   el_src = (const int*)d_in[4];
    const int*   el_dst = (const int*)d_in[5];
    const float* Wl_ui1 = (const float*)d_in[6];
    const float* b_ui1  = (const float*)d_in[7];
    const float* Wr_ui1 = (const float*)d_in[8];
    const float* Wl_iu1 = (const float*)d_in[9];
    const float* b_iu1  = (const float*)d_in[10];
    const float* Wr_iu1 = (const float*)d_in[11];
    const float* Wl_ui2 = (const float*)d_in[12];
    const float* b_ui2  = (const float*)d_in[13];
    const float* Wr_ui2 = (const float*)d_in[14];
    const float* Wl_iu2 = (const float*)d_in[15];
    const float* b_iu2  = (const float*)d_in[16];
    const float* Wr_iu2 = (const float*)d_in[17];
    float* out = (float*)d_out;

    // ---- workspace layout ----
    // int region (element offsets): cnt_i 0, cnt_u 50000, bsum_i 150000,
    // bsum_u 150064, head_i 150192, head_u 200192, nbr_i 300192,
    // nbr_u 940192, end 1580192 ints = 6,320,768 B.
    int* iw     = (int*)d_ws;
    int* cnt_i  = iw;
    int* cnt_u  = iw + 50000;
    int* bsum_i = iw + 150000;
    int* bsum_u = iw + 150064;
    int* head_i = iw + 150192;
    int* head_u = iw + 200192;
    int* nbr_i  = iw + 300192;
    int* nbr_u  = iw + 940192;
    char* W8 = (char*)d_ws;
    size_t off = 6320768;
    ushort_t* Bh1u = (ushort_t*)(W8 + off); off += 65536;
    ushort_t* Bl1u = (ushort_t*)(W8 + off); off += 65536;
    ushort_t* Bh1i = (ushort_t*)(W8 + off); off += 65536;
    ushort_t* Bl1i = (ushort_t*)(W8 + off); off += 65536;
    ushort_t* Bh2u = (ushort_t*)(W8 + off); off += 32768;
    ushort_t* Bl2u = (ushort_t*)(W8 + off); off += 32768;
    ushort_t* Bh2i = (ushort_t*)(W8 + off); off += 32768;
    ushort_t* Bl2i = (ushort_t*)(W8 + off); off += 32768;   // off = 6,713,984
    ushort_t* h1_u = (ushort_t*)(W8 + off); off += (size_t)NUSER * 128 * 2;  // 25.6 MB
    ushort_t* h1_i = (ushort_t*)(W8 + off); off += (size_t)NITEM * 128 * 2;  // 12.8 MB
    size_t YB = off;                                        // 45,113,984
    // layer-1 view
    ushort_t* ymsg_u = (ushort_t*)(W8 + YB);                 // 25.6 MB
    ushort_t* ymsg_i = (ushort_t*)(W8 + YB + 25600000);      // 12.8 MB
    ushort_t* z_u    = (ushort_t*)(W8 + YB + 38400000);      // 25.6 MB
    ushort_t* z_i    = (ushort_t*)(W8 + YB + 64000000);      // 12.8 MB
    // layer-2 view (layer-1 buffers dead by each use point)
    ushort_t* ymsg2_u = (ushort_t*)(W8 + YB);                // 12.8 MB
    ushort_t* ymsg2_i = (ushort_t*)(W8 + YB + 12800000);     //  6.4 MB
    ushort_t* z2_u    = (ushort_t*)(W8 + YB + 19200000);     // 12.8 MB
    ushort_t* z2_i    = (ushort_t*)(W8 + YB + 32000000);     //  6.4 MB
    ushort_t* h2_u    = (ushort_t*)(W8 + YB + 38400000);     // 12.8 MB (bf16)
    ushort_t* h2_i    = (ushort_t*)(W8 + YB + 51200000);     //  6.4 MB (bf16)
    size_t total_ws = YB + 76800000;                         // 121,913,984 B

    // Full-footprint clear: every call (incl. graph replays) starts from an
    // identical workspace state. (Round-3 lesson: partial clear diverged.)
    hipMemsetAsync(d_ws, 0, total_ws, stream);

    // ---- CSR build: count -> ordered exclusive scan -> binned fill ----
    count_kernel<<<(NEDGE + 255) / 256, 256, 0, stream>>>(src_u, dst_i, cnt_u, cnt_i);
    scan1_kernel<<<GI + GU, 256, 0, stream>>>(cnt_i, cnt_u, head_i, head_u, bsum_i, bsum_u);
    scan2_kernel<<<1, 256, 0, stream>>>(bsum_i, bsum_u);
    scan3_kernel<<<GI + GU, 256, 0, stream>>>(head_i, head_u, bsum_i, bsum_u);
    fillb_kernel<<<8 * 2 * FNCH, 256, 0, stream>>>(src_u, dst_i, head_i, head_u, nbr_i, nbr_u);

    // ---- weight packing (all 4 sets, one dispatch) ----
    wprep_kernel<<<48, 256, 0, stream>>>(Wl_ui1, Wr_iu1, Wl_iu1, Wr_ui1,
                                         Wl_ui2, Wr_iu2, Wl_iu2, Wr_ui2,
                                         Bh1u, Bl1u, Bh1i, Bl1i,
                                         Bh2u, Bl2u, Bh2i, Bl2i);

    // ---- layer 1: transform first (linearity of mean-agg), then gather ----
    gemm_kernel<256, true><<<3125 + 1563, 256, 0, stream>>>(
        x_user, x_item, Bh1u, Bl1u, Bh1i, Bl1i,
        ymsg_u, z_u, ymsg_i, z_i, NUSER, NITEM, 3125);
    gather1_kernel<<<(NITEM + NUSER) / 4, 256, 0, stream>>>(
        ymsg_u, ymsg_i, nbr_i, head_i, cnt_i, nbr_u, head_u, cnt_u,
        z_i, z_u, b_ui1, b_iu1, h1_i, h1_u);

    // ---- layer 2 ----
    gemm_kernel<128, false><<<3125 + 1563, 256, 0, stream>>>(
        h1_u, h1_i, Bh2u, Bl2u, Bh2i, Bl2i,
        ymsg2_u, z2_u, ymsg2_i, z2_i, NUSER, NITEM, 3125);
    gather2_kernel<<<(NITEM + NUSER) / 4, 256, 0, stream>>>(
        ymsg2_u, ymsg2_i, nbr_i, head_i, cnt_i, nbr_u, head_u, cnt_u,
        z2_i, z2_u, b_ui2, b_iu2, h2_i, h2_u);

    // ---- link prediction head ----
    predict_kernel<<<NLINK / 4, 256, 0, stream>>>(el_src, el_dst, h2_u, h2_i, out);
}

// Round 6
// 353.540 us; speedup vs baseline: 13.7540x; 1.0728x over previous
//
#include <hip/hip_runtime.h>

#define NUSER 100000
#define NITEM 50000
#define NEDGE 640000
#define NLINK 200000
#define GI 49   // ceil(NITEM/1024)
#define GU 98   // ceil(NUSER/1024)
// F0 = F1 = 128, F2 = 64

typedef unsigned int  uint;
typedef unsigned short ushort_t;
typedef __attribute__((ext_vector_type(8))) short bf16x8;
typedef __attribute__((ext_vector_type(4))) float f32x4;
typedef __attribute__((ext_vector_type(4))) uint  u32x4;

__device__ __forceinline__ ushort_t f2bf(float f) {           // RNE f32 -> bf16
    uint u = __float_as_uint(f);
    u += 0x7FFFu + ((u >> 16) & 1u);
    return (ushort_t)(u >> 16);
}
__device__ __forceinline__ float bf2f(ushort_t h) { return __uint_as_float(((uint)h) << 16); }
__device__ __forceinline__ float lo16f(uint u) { return __uint_as_float(u << 16); }
__device__ __forceinline__ float hi16f(uint u) { return __uint_as_float(u & 0xFFFF0000u); }

// ---------------------------------------------------------------------------
// Fused [degree count | weight pack]. Blocks [0,2500): count edges (atomics on
// zeroed cnt). Blocks [2500,2548): pack the 4 B=[Wl|Wr] pairs into MFMA
// fragment order, split bf16 hi/lo. Layout: Bh/Bl[nt][ks][lane][j];
// col = nt*16+(lane&15), k = ks*32+(lane>>4)*8+j.
// ---------------------------------------------------------------------------
__global__ __launch_bounds__(256) void countw_kernel(
    const int* __restrict__ src, const int* __restrict__ dst,
    int* __restrict__ cnt_u, int* __restrict__ cnt_i,
    const float* __restrict__ Wl0, const float* __restrict__ Wr0,
    const float* __restrict__ Wl1, const float* __restrict__ Wr1,
    const float* __restrict__ Wl2, const float* __restrict__ Wr2,
    const float* __restrict__ Wl3, const float* __restrict__ Wr3,
    ushort_t* __restrict__ Bh0, ushort_t* __restrict__ Bl0,
    ushort_t* __restrict__ Bh1, ushort_t* __restrict__ Bl1,
    ushort_t* __restrict__ Bh2, ushort_t* __restrict__ Bl2,
    ushort_t* __restrict__ Bh3, ushort_t* __restrict__ Bl3)
{
    if (blockIdx.x < 2500) {
        int e = blockIdx.x * 256 + threadIdx.x;
        if (e >= NEDGE) return;
        atomicAdd(&cnt_u[src[e]], 1);
        atomicAdd(&cnt_i[dst[e]], 1);
        return;
    }
    int b = blockIdx.x - 2500;
    const float *Wl, *Wr; ushort_t *Bh, *Bl; int FO, t;
    if (b < 16)      { Wl = Wl0; Wr = Wr0; Bh = Bh0; Bl = Bl0; FO = 128; t = b * 256 + threadIdx.x; }
    else if (b < 32) { Wl = Wl1; Wr = Wr1; Bh = Bh1; Bl = Bl1; FO = 128; t = (b - 16) * 256 + threadIdx.x; }
    else if (b < 40) { Wl = Wl2; Wr = Wr2; Bh = Bh2; Bl = Bl2; FO = 64;  t = (b - 32) * 256 + threadIdx.x; }
    else             { Wl = Wl3; Wr = Wr3; Bh = Bh3; Bl = Bl3; FO = 64;  t = (b - 40) * 256 + threadIdx.x; }
    int lane = t & 63, ks = (t >> 6) & 3, nt = t >> 8;
    int col = nt * 16 + (lane & 15);
    int k0 = ks * 32 + (lane >> 4) * 8;
    const float* W = (col < FO) ? Wl : Wr;
    int cc = (col < FO) ? col : col - FO;
#pragma unroll
    for (int j = 0; j < 8; ++j) {
        float v = W[(size_t)(k0 + j) * FO + cc];
        ushort_t h = f2bf(v);
        Bh[(size_t)t * 8 + j] = h;
        Bl[(size_t)t * 8 + j] = f2bf(v - bf2f(h));
    }
}

// ---------------------------------------------------------------------------
// Ordered exclusive scan of cnt -> head. scan1: per-1024-chunk local
// exclusive scan + chunk sum to bsum.
// ---------------------------------------------------------------------------
__global__ __launch_bounds__(256) void scan1_kernel(
    const int* __restrict__ cnt_i, const int* __restrict__ cnt_u,
    int* __restrict__ head_i, int* __restrict__ head_u,
    int* __restrict__ bsum_i, int* __restrict__ bsum_u)
{
    __shared__ int sh[256];
    int b = blockIdx.x, t = threadIdx.x;
    const int* cnt; int* head; int* bsum; int n, cb;
    if (b < GI) { cnt = cnt_i; head = head_i; bsum = bsum_i; n = NITEM; cb = b; }
    else        { cnt = cnt_u; head = head_u; bsum = bsum_u; n = NUSER; cb = b - GI; }
    int base = cb * 1024 + t * 4;
    int4 v = {0, 0, 0, 0};
    if (base + 3 < n) v = *(const int4*)(cnt + base);
    else {
        if (base + 0 < n) v.x = cnt[base + 0];
        if (base + 1 < n) v.y = cnt[base + 1];
        if (base + 2 < n) v.z = cnt[base + 2];
    }
    int s = v.x + v.y + v.z + v.w;
    sh[t] = s;
    __syncthreads();
    for (int o = 1; o < 256; o <<= 1) {
        int a = (t >= o) ? sh[t - o] : 0;
        __syncthreads();
        sh[t] += a;
        __syncthreads();
    }
    int excl = sh[t] - s;
    if (t == 255) bsum[cb] = sh[255];
    if (base + 0 < n) head[base + 0] = excl;
    if (base + 1 < n) head[base + 1] = excl + v.x;
    if (base + 2 < n) head[base + 2] = excl + v.x + v.y;
    if (base + 3 < n) head[base + 3] = excl + v.x + v.y + v.z;
}

// ---------------------------------------------------------------------------
// scan23: block cb computes add = sum(bsum[0..cb)) in LDS (redundant but tiny)
// and adds it to its head chunk. bsum is read-only (no cross-block hazard).
// ---------------------------------------------------------------------------
__global__ __launch_bounds__(256) void scan23_kernel(
    int* __restrict__ head_i, int* __restrict__ head_u,
    const int* __restrict__ bsum_i, const int* __restrict__ bsum_u)
{
    __shared__ int sh[256];
    int b = blockIdx.x, t = threadIdx.x;
    int* head; const int* bsum; int n, cb;
    if (b < GI) { head = head_i; bsum = bsum_i; n = NITEM; cb = b; }
    else        { head = head_u; bsum = bsum_u; n = NUSER; cb = b - GI; }
    sh[t] = (t < cb) ? bsum[t] : 0;
    __syncthreads();
    for (int o = 128; o >= 1; o >>= 1) {
        if (t < o) sh[t] += sh[t + o];
        __syncthreads();
    }
    int add = sh[0];
    int base = cb * 1024 + t * 4;
#pragma unroll
    for (int k = 0; k < 4; ++k)
        if (base + k < n) head[base + k] += add;
}

// ---------------------------------------------------------------------------
// Fused [layer-1 GEMM | binned fill].
// GEMM blocks [0, 4688): out[n x 256] = A[n x 128] @ B[128 x 256], A f32
// hi/lo-split in LDS staging (3 MFMA products); cols[0,128)->ymsg bf16,
// [128,256)->z bf16. 4 waves, 32 rows/block, 16B-chunk XOR LDS swizzle.
// Fill blocks [4688, 9696): 8 node-range passes x 2 dirs x 313 edge chunks;
// ordered head offsets confine scattered nbr stores to ~320KB L2 windows.
// ---------------------------------------------------------------------------
#define FCHUNK 2048
#define FNCH   313   // ceil(NEDGE / FCHUNK)
#define NBG1   4688  // 3125 user + 1563 item gemm blocks
__global__ __launch_bounds__(256) void gemmfill_kernel(
    const float* __restrict__ xu, const float* __restrict__ xi,
    const ushort_t* __restrict__ Bh0, const ushort_t* __restrict__ Bl0,
    const ushort_t* __restrict__ Bh1, const ushort_t* __restrict__ Bl1,
    ushort_t* __restrict__ y0, ushort_t* __restrict__ z0,
    ushort_t* __restrict__ y1, ushort_t* __restrict__ z1,
    const int* __restrict__ src, const int* __restrict__ dst,
    int* __restrict__ head_i, int* __restrict__ head_u,
    int* __restrict__ nbr_i, int* __restrict__ nbr_u)
{
    if (blockIdx.x >= NBG1) {
        int b = blockIdx.x - NBG1;
        int pass = b / (2 * FNCH);
        int rem  = b % (2 * FNCH);
        int dir  = rem / FNCH;
        int base = (rem % FNCH) * FCHUNK;
        int e_end = min(base + FCHUNK, NEDGE);
        if (dir == 0) {
            int lo = pass * (NITEM / 8), hi = lo + NITEM / 8;
            for (int e = base + threadIdx.x; e < e_end; e += 256) {
                int d = dst[e];
                if (d >= lo && d < hi) nbr_i[atomicAdd(&head_i[d], 1)] = src[e];
            }
        } else {
            int lo = pass * (NUSER / 8), hi = lo + NUSER / 8;
            for (int e = base + threadIdx.x; e < e_end; e += 256) {
                int s = src[e];
                if (s >= lo && s < hi) nbr_u[atomicAdd(&head_u[s], 1)] = dst[e];
            }
        }
        return;
    }

    __shared__ u32x4 ashH[32][16];
    __shared__ u32x4 ashL[32][16];
    const int tid = threadIdx.x;
    const float* A; const ushort_t *Bh, *Bl; ushort_t *ymsg, *zout; int n, row0;
    if ((int)blockIdx.x < 3125) { A = xu; Bh = Bh0; Bl = Bl0; ymsg = y0; zout = z0; n = NUSER; row0 = blockIdx.x * 32; }
    else { A = xi; Bh = Bh1; Bl = Bl1; ymsg = y1; zout = z1; n = NITEM; row0 = (blockIdx.x - 3125) * 32; }

#pragma unroll
    for (int i = 0; i < 2; ++i) {
        int idx = i * 256 + tid;
        int row = idx >> 4, ch = idx & 15;
        int grow = row0 + row;
        f32x4 f0 = {0.f, 0.f, 0.f, 0.f}, f1 = {0.f, 0.f, 0.f, 0.f};
        if (grow < n) {
            const f32x4* p = (const f32x4*)(A + (size_t)grow * 128 + ch * 8);
            f0 = p[0]; f1 = p[1];
        }
        float e[8];
#pragma unroll
        for (int j = 0; j < 4; ++j) { e[j] = f0[j]; e[4 + j] = f1[j]; }
        uint hv[4], lv[4];
#pragma unroll
        for (int j = 0; j < 4; ++j) {
            ushort_t h0 = f2bf(e[2 * j]), h1 = f2bf(e[2 * j + 1]);
            hv[j] = (uint)h0 | ((uint)h1 << 16);
            ushort_t l0 = f2bf(e[2 * j] - bf2f(h0)), l1 = f2bf(e[2 * j + 1] - bf2f(h1));
            lv[j] = (uint)l0 | ((uint)l1 << 16);
        }
        int sc = ch ^ (row & 7);
        u32x4 hq = {hv[0], hv[1], hv[2], hv[3]};
        u32x4 lq = {lv[0], lv[1], lv[2], lv[3]};
        ashH[row][sc] = hq;
        ashL[row][sc] = lq;
    }
    __syncthreads();

    const int lane = tid & 63, wv = tid >> 6;
    const int lr = lane & 15, lg = lane >> 4;
    const int colbase = wv * 64;
    f32x4 acc[2][4];
#pragma unroll
    for (int rt = 0; rt < 2; ++rt)
#pragma unroll
        for (int ct = 0; ct < 4; ++ct) { f32x4 zz = {0.f, 0.f, 0.f, 0.f}; acc[rt][ct] = zz; }

#pragma unroll
    for (int ks = 0; ks < 4; ++ks) {
        bf16x8 ah[2], al[2];
#pragma unroll
        for (int rt = 0; rt < 2; ++rt) {
            int row = rt * 16 + lr;
            int pos = (ks * 4 + lg) ^ (row & 7);
            ah[rt] = __builtin_bit_cast(bf16x8, ashH[row][pos]);
            al[rt] = __builtin_bit_cast(bf16x8, ashL[row][pos]);
        }
#pragma unroll
        for (int ct = 0; ct < 4; ++ct) {
            int nt = (colbase >> 4) + ct;
            size_t off = ((size_t)(nt * 4 + ks) * 64 + lane) * 8;
            bf16x8 bh = __builtin_bit_cast(bf16x8, *(const u32x4*)(Bh + off));
            bf16x8 bl = __builtin_bit_cast(bf16x8, *(const u32x4*)(Bl + off));
#pragma unroll
            for (int rt = 0; rt < 2; ++rt) {
                acc[rt][ct] = __builtin_amdgcn_mfma_f32_16x16x32_bf16(ah[rt], bh, acc[rt][ct], 0, 0, 0);
                acc[rt][ct] = __builtin_amdgcn_mfma_f32_16x16x32_bf16(ah[rt], bl, acc[rt][ct], 0, 0, 0);
                acc[rt][ct] = __builtin_amdgcn_mfma_f32_16x16x32_bf16(al[rt], bh, acc[rt][ct], 0, 0, 0);
            }
        }
    }

    // C/D layout (m89-verified): col = lane&15, row = (lane>>4)*4 + reg
#pragma unroll
    for (int rt = 0; rt < 2; ++rt)
#pragma unroll
        for (int ct = 0; ct < 4; ++ct) {
            int col = colbase + ct * 16 + lr;
            bool ism = col < 128;
            ushort_t* dstp = ism ? ymsg : zout;
            int cc = ism ? col : col - 128;
#pragma unroll
            for (int r = 0; r < 4; ++r) {
                int row = row0 + rt * 16 + lg * 4 + r;
                if (row < n) dstp[(size_t)row * 128 + cc] = f2bf(acc[rt][ct][r]);
            }
        }
}

// ---------------------------------------------------------------------------
// Layer-2 GEMM (both node types, one dispatch): A bf16 (2 products, B split).
// ---------------------------------------------------------------------------
__global__ __launch_bounds__(256) void gemm2_kernel(
    const ushort_t* __restrict__ A0, const ushort_t* __restrict__ A1,
    const ushort_t* __restrict__ Bh0, const ushort_t* __restrict__ Bl0,
    const ushort_t* __restrict__ Bh1, const ushort_t* __restrict__ Bl1,
    ushort_t* __restrict__ y0, ushort_t* __restrict__ z0,
    ushort_t* __restrict__ y1, ushort_t* __restrict__ z1,
    int n0, int n1, int nb0)
{
    __shared__ u32x4 ashH[32][16];
    const int tid = threadIdx.x;
    const ushort_t* A; const ushort_t *Bh, *Bl; ushort_t *ymsg, *zout; int n, row0;
    if ((int)blockIdx.x < nb0) { A = A0; Bh = Bh0; Bl = Bl0; ymsg = y0; zout = z0; n = n0; row0 = blockIdx.x * 32; }
    else { A = A1; Bh = Bh1; Bl = Bl1; ymsg = y1; zout = z1; n = n1; row0 = (blockIdx.x - nb0) * 32; }

#pragma unroll
    for (int i = 0; i < 2; ++i) {
        int idx = i * 256 + tid;
        int row = idx >> 4, ch = idx & 15;
        int grow = row0 + row;
        u32x4 q = {0u, 0u, 0u, 0u};
        if (grow < n) q = *(const u32x4*)(A + (size_t)grow * 128 + ch * 8);
        ashH[row][ch ^ (row & 7)] = q;
    }
    __syncthreads();

    const int lane = tid & 63, wv = tid >> 6;
    const int lr = lane & 15, lg = lane >> 4;
    const int colbase = wv * 32;
    f32x4 acc[2][2];
#pragma unroll
    for (int rt = 0; rt < 2; ++rt)
#pragma unroll
        for (int ct = 0; ct < 2; ++ct) { f32x4 zz = {0.f, 0.f, 0.f, 0.f}; acc[rt][ct] = zz; }

#pragma unroll
    for (int ks = 0; ks < 4; ++ks) {
        bf16x8 ah[2];
#pragma unroll
        for (int rt = 0; rt < 2; ++rt) {
            int row = rt * 16 + lr;
            int pos = (ks * 4 + lg) ^ (row & 7);
            ah[rt] = __builtin_bit_cast(bf16x8, ashH[row][pos]);
        }
#pragma unroll
        for (int ct = 0; ct < 2; ++ct) {
            int nt = (colbase >> 4) + ct;
            size_t off = ((size_t)(nt * 4 + ks) * 64 + lane) * 8;
            bf16x8 bh = __builtin_bit_cast(bf16x8, *(const u32x4*)(Bh + off));
            bf16x8 bl = __builtin_bit_cast(bf16x8, *(const u32x4*)(Bl + off));
#pragma unroll
            for (int rt = 0; rt < 2; ++rt) {
                acc[rt][ct] = __builtin_amdgcn_mfma_f32_16x16x32_bf16(ah[rt], bh, acc[rt][ct], 0, 0, 0);
                acc[rt][ct] = __builtin_amdgcn_mfma_f32_16x16x32_bf16(ah[rt], bl, acc[rt][ct], 0, 0, 0);
            }
        }
    }

#pragma unroll
    for (int rt = 0; rt < 2; ++rt)
#pragma unroll
        for (int ct = 0; ct < 2; ++ct) {
            int col = colbase + ct * 16 + lr;
            bool ism = col < 64;
            ushort_t* dstp = ism ? ymsg : zout;
            int cc = ism ? col : col - 64;
#pragma unroll
            for (int r = 0; r < 4; ++r) {
                int row = row0 + rt * 16 + lg * 4 + r;
                if (row < n) dstp[(size_t)row * 64 + cc] = f2bf(acc[rt][ct][r]);
            }
        }
}

// ---------------------------------------------------------------------------
// Layer-1 gather + epilogue (items then users, one dispatch), width 128:
// h1 = relu(mean(ymsg[nbr]) + z + b) as bf16. One wave/node, lane owns 2 cols.
// ---------------------------------------------------------------------------
__global__ __launch_bounds__(256) void gather1_kernel(
    const ushort_t* __restrict__ ymsg_u, const ushort_t* __restrict__ ymsg_i,
    const int* __restrict__ nbr_i, const int* __restrict__ head_i, const int* __restrict__ cnt_i,
    const int* __restrict__ nbr_u, const int* __restrict__ head_u, const int* __restrict__ cnt_u,
    const ushort_t* __restrict__ z_i, const ushort_t* __restrict__ z_u,
    const float* __restrict__ b_ui, const float* __restrict__ b_iu,
    ushort_t* __restrict__ h1_i, ushort_t* __restrict__ h1_u)
{
    int w = (blockIdx.x << 2) + (threadIdx.x >> 6);
    const ushort_t *ym, *z; const int *nbr, *head, *cnt; const float* bias;
    ushort_t* hout; int node;
    if (w < NITEM) { ym = ymsg_u; nbr = nbr_i; head = head_i; cnt = cnt_i; z = z_i; bias = b_ui; hout = h1_i; node = w; }
    else if (w < NITEM + NUSER) { ym = ymsg_i; nbr = nbr_u; head = head_u; cnt = cnt_u; z = z_u; bias = b_iu; hout = h1_u; node = w - NITEM; }
    else return;
    int lane = threadIdx.x & 63;
    int c = cnt[node], end = head[node];
    int j = end - c;
    const uint* Y = (const uint*)ym;
    float ax = 0.f, ay = 0.f;
    for (; j + 7 < end; j += 8) {
        uint u0 = Y[(size_t)nbr[j + 0] * 64 + lane];
        uint u1 = Y[(size_t)nbr[j + 1] * 64 + lane];
        uint u2 = Y[(size_t)nbr[j + 2] * 64 + lane];
        uint u3 = Y[(size_t)nbr[j + 3] * 64 + lane];
        uint u4 = Y[(size_t)nbr[j + 4] * 64 + lane];
        uint u5 = Y[(size_t)nbr[j + 5] * 64 + lane];
        uint u6 = Y[(size_t)nbr[j + 6] * 64 + lane];
        uint u7 = Y[(size_t)nbr[j + 7] * 64 + lane];
        ax += lo16f(u0) + lo16f(u1) + lo16f(u2) + lo16f(u3)
            + lo16f(u4) + lo16f(u5) + lo16f(u6) + lo16f(u7);
        ay += hi16f(u0) + hi16f(u1) + hi16f(u2) + hi16f(u3)
            + hi16f(u4) + hi16f(u5) + hi16f(u6) + hi16f(u7);
    }
    for (; j + 1 < end; j += 2) {
        uint u0 = Y[(size_t)nbr[j + 0] * 64 + lane];
        uint u1 = Y[(size_t)nbr[j + 1] * 64 + lane];
        ax += lo16f(u0) + lo16f(u1);
        ay += hi16f(u0) + hi16f(u1);
    }
    if (j < end) {
        uint u0 = Y[(size_t)nbr[j] * 64 + lane];
        ax += lo16f(u0); ay += hi16f(u0);
    }
    float m = 1.f / fmaxf((float)c, 1.f);
    uint zu = ((const uint*)z)[(size_t)node * 64 + lane];
    float vx = fmaxf(ax * m + lo16f(zu) + bias[lane * 2], 0.f);
    float vy = fmaxf(ay * m + hi16f(zu) + bias[lane * 2 + 1], 0.f);
    ((uint*)hout)[(size_t)node * 64 + lane] = (uint)f2bf(vx) | ((uint)f2bf(vy) << 16);
}

// ---------------------------------------------------------------------------
// Layer-2 gather + epilogue (items then users), width 64, no relu, bf16 out.
// ---------------------------------------------------------------------------
__global__ __launch_bounds__(256) void gather2_kernel(
    const ushort_t* __restrict__ ymsg_u, const ushort_t* __restrict__ ymsg_i,
    const int* __restrict__ nbr_i, const int* __restrict__ head_i, const int* __restrict__ cnt_i,
    const int* __restrict__ nbr_u, const int* __restrict__ head_u, const int* __restrict__ cnt_u,
    const ushort_t* __restrict__ z_i, const ushort_t* __restrict__ z_u,
    const float* __restrict__ b_ui, const float* __restrict__ b_iu,
    ushort_t* __restrict__ h2_i, ushort_t* __restrict__ h2_u)
{
    int w = (blockIdx.x << 2) + (threadIdx.x >> 6);
    const ushort_t *ym, *z; const int *nbr, *head, *cnt; const float* bias;
    ushort_t* hout; int node;
    if (w < NITEM) { ym = ymsg_u; nbr = nbr_i; head = head_i; cnt = cnt_i; z = z_i; bias = b_ui; hout = h2_i; node = w; }
    else if (w < NITEM + NUSER) { ym = ymsg_i; nbr = nbr_u; head = head_u; cnt = cnt_u; z = z_u; bias = b_iu; hout = h2_u; node = w - NITEM; }
    else return;
    int lane = threadIdx.x & 63;
    int c = cnt[node], end = head[node];
    int j = end - c;
    float a = 0.f;
    for (; j + 7 < end; j += 8) {
        a += bf2f(ym[(size_t)nbr[j + 0] * 64 + lane]) + bf2f(ym[(size_t)nbr[j + 1] * 64 + lane])
           + bf2f(ym[(size_t)nbr[j + 2] * 64 + lane]) + bf2f(ym[(size_t)nbr[j + 3] * 64 + lane])
           + bf2f(ym[(size_t)nbr[j + 4] * 64 + lane]) + bf2f(ym[(size_t)nbr[j + 5] * 64 + lane])
           + bf2f(ym[(size_t)nbr[j + 6] * 64 + lane]) + bf2f(ym[(size_t)nbr[j + 7] * 64 + lane]);
    }
    for (; j + 1 < end; j += 2)
        a += bf2f(ym[(size_t)nbr[j] * 64 + lane]) + bf2f(ym[(size_t)nbr[j + 1] * 64 + lane]);
    if (j < end) a += bf2f(ym[(size_t)nbr[j] * 64 + lane]);
    float m = 1.f / fmaxf((float)c, 1.f);
    float v = a * m + bf2f(z[(size_t)node * 64 + lane]) + bias[lane];
    hout[(size_t)node * 64 + lane] = f2bf(v);
}

// ---------------------------------------------------------------------------
// Link head: pred[l] = dot64(h_u2[el_src[l]], h_i2[el_dst[l]]), bf16 h rows.
// ---------------------------------------------------------------------------
__global__ __launch_bounds__(256) void predict_kernel(
    const int* __restrict__ el_src, const int* __restrict__ el_dst,
    const ushort_t* __restrict__ hu, const ushort_t* __restrict__ hi,
    float* __restrict__ out)
{
    int l = (blockIdx.x << 2) + (threadIdx.x >> 6);
    if (l >= NLINK) return;
    int lane = threadIdx.x & 63;
    int u = el_src[l];
    int it = el_dst[l];
    float v = bf2f(hu[(size_t)u * 64 + lane]) * bf2f(hi[(size_t)it * 64 + lane]);
#pragma unroll
    for (int o = 32; o >= 1; o >>= 1) v += __shfl_down(v, o, 64);
    if (lane == 0) out[l] = v;
}

extern "C" void kernel_launch(void* const* d_in, const int* in_sizes, int n_in,
                              void* d_out, int out_size, void* d_ws, size_t ws_size,
                              hipStream_t stream) {
    const float* x_user = (const float*)d_in[0];
    const float* x_item = (const float*)d_in[1];
    const int*   src_u  = (const int*)d_in[2];
    const int*   dst_i  = (const int*)d_in[3];
    const int*   el_src = (const int*)d_in[4];
    const int*   el_dst = (const int*)d_in[5];
    const float* Wl_ui1 = (const float*)d_in[6];
    const float* b_ui1  = (const float*)d_in[7];
    const float* Wr_ui1 = (const float*)d_in[8];
    const float* Wl_iu1 = (const float*)d_in[9];
    const float* b_iu1  = (const float*)d_in[10];
    const float* Wr_iu1 = (const float*)d_in[11];
    const float* Wl_ui2 = (const float*)d_in[12];
    const float* b_ui2  = (const float*)d_in[13];
    const float* Wr_ui2 = (const float*)d_in[14];
    const float* Wl_iu2 = (const float*)d_in[15];
    const float* b_iu2  = (const float*)d_in[16];
    const float* Wr_iu2 = (const float*)d_in[17];
    float* out = (float*)d_out;

    // ---- workspace layout (same as round 5) ----
    int* iw     = (int*)d_ws;
    int* cnt_i  = iw;              // [0, 50000)
    int* cnt_u  = iw + 50000;      // [50000, 150000)
    int* bsum_i = iw + 150000;     // 64 slots
    int* bsum_u = iw + 150064;     // 128 slots
    int* head_i = iw + 150192;
    int* head_u = iw + 200192;
    int* nbr_i  = iw + 300192;
    int* nbr_u  = iw + 940192;
    char* W8 = (char*)d_ws;
    size_t off = 6320768;
    ushort_t* Bh1u = (ushort_t*)(W8 + off); off += 65536;
    ushort_t* Bl1u = (ushort_t*)(W8 + off); off += 65536;
    ushort_t* Bh1i = (ushort_t*)(W8 + off); off += 65536;
    ushort_t* Bl1i = (ushort_t*)(W8 + off); off += 65536;
    ushort_t* Bh2u = (ushort_t*)(W8 + off); off += 32768;
    ushort_t* Bl2u = (ushort_t*)(W8 + off); off += 32768;
    ushort_t* Bh2i = (ushort_t*)(W8 + off); off += 32768;
    ushort_t* Bl2i = (ushort_t*)(W8 + off); off += 32768;   // off = 6,713,984
    ushort_t* h1_u = (ushort_t*)(W8 + off); off += (size_t)NUSER * 128 * 2;
    ushort_t* h1_i = (ushort_t*)(W8 + off); off += (size_t)NITEM * 128 * 2;
    size_t YB = off;                                        // 45,113,984
    ushort_t* ymsg_u = (ushort_t*)(W8 + YB);
    ushort_t* ymsg_i = (ushort_t*)(W8 + YB + 25600000);
    ushort_t* z_u    = (ushort_t*)(W8 + YB + 38400000);
    ushort_t* z_i    = (ushort_t*)(W8 + YB + 64000000);
    ushort_t* ymsg2_u = (ushort_t*)(W8 + YB);
    ushort_t* ymsg2_i = (ushort_t*)(W8 + YB + 12800000);
    ushort_t* z2_u    = (ushort_t*)(W8 + YB + 19200000);
    ushort_t* z2_i    = (ushort_t*)(W8 + YB + 32000000);
    ushort_t* h2_u    = (ushort_t*)(W8 + YB + 38400000);
    ushort_t* h2_i    = (ushort_t*)(W8 + YB + 51200000);

    // Zero ONLY cnt (atomic-incremented). Every other ws buffer is fully
    // written before it is read each call: head by scan, nbr by fillb
    // (sum(cnt)=E claims every slot), B by wprep, ymsg/z/h by gemm/gather.
    hipMemsetAsync(d_ws, 0, 150000 * sizeof(int), stream);

    // ---- [degree count | weight pack] ----
    countw_kernel<<<2548, 256, 0, stream>>>(
        src_u, dst_i, cnt_u, cnt_i,
        Wl_ui1, Wr_iu1, Wl_iu1, Wr_ui1, Wl_ui2, Wr_iu2, Wl_iu2, Wr_ui2,
        Bh1u, Bl1u, Bh1i, Bl1i, Bh2u, Bl2u, Bh2i, Bl2i);

    // ---- ordered exclusive scan ----
    scan1_kernel<<<GI + GU, 256, 0, stream>>>(cnt_i, cnt_u, head_i, head_u, bsum_i, bsum_u);
    scan23_kernel<<<GI + GU, 256, 0, stream>>>(head_i, head_u, bsum_i, bsum_u);

    // ---- [layer-1 GEMM (transform-first) | binned CSR fill] ----
    gemmfill_kernel<<<NBG1 + 8 * 2 * FNCH, 256, 0, stream>>>(
        x_user, x_item, Bh1u, Bl1u, Bh1i, Bl1i,
        ymsg_u, z_u, ymsg_i, z_i,
        src_u, dst_i, head_i, head_u, nbr_i, nbr_u);

    // ---- layer 1 gather ----
    gather1_kernel<<<(NITEM + NUSER) / 4, 256, 0, stream>>>(
        ymsg_u, ymsg_i, nbr_i, head_i, cnt_i, nbr_u, head_u, cnt_u,
        z_i, z_u, b_ui1, b_iu1, h1_i, h1_u);

    // ---- layer 2 ----
    gemm2_kernel<<<3125 + 1563, 256, 0, stream>>>(
        h1_u, h1_i, Bh2u, Bl2u, Bh2i, Bl2i,
        ymsg2_u, z2_u, ymsg2_i, z2_i, NUSER, NITEM, 3125);
    gather2_kernel<<<(NITEM + NUSER) / 4, 256, 0, stream>>>(
        ymsg2_u, ymsg2_i, nbr_i, head_i, cnt_i, nbr_u, head_u, cnt_u,
        z2_i, z2_u, b_ui2, b_iu2, h2_i, h2_u);

    // ---- link prediction head ----
    predict_kernel<<<NLINK / 4, 256, 0, stream>>>(el_src, el_dst, h2_u, h2_i, out);
}